// Round 9
// baseline (568.471 us; speedup 1.0000x reference)
//
#include <hip/hip_runtime.h>
#include <cstdint>
#include <cstddef>

#define NVv 192
#define NAa 64
#define TT 128
#define FDd 1024
#define CCc 128
#define EEe 262144
#define NNn 32768

typedef _Float16 f16x8 __attribute__((ext_vector_type(8)));
typedef float f32x4 __attribute__((ext_vector_type(4)));

// list arena capacities/offsets (int2 units): vpa, aud, acv, m1, m2, m3
#define CAP0 65536
#define CAP1 65536
#define CAP2 65536
#define CAP3 98304
#define CAP4 98304
#define CAP5 147456
#define ARENA_TOTAL (CAP0+CAP1+CAP2+CAP3+CAP4+CAP5)   // 540672

__device__ __forceinline__ void eval_masks(int a, bool m[6]) {
    m[0] = (a == -3); m[1] = (a == -2); m[2] = (a == 3);
    m[3] = (a >= 0) & (a <= 1);
    m[4] = (a >= -1) & (a <= 0);
    m[5] = (a >= -1) & (a <= 1);
}

// ---------------- zero fill (1024 floats / block) ----------------
__global__ __launch_bounds__(256) void k_zero(float* __restrict__ p) {
    size_t i = (size_t)blockIdx.x * 1024 + (size_t)threadIdx.x * 4;
    *(float4*)(p + i) = make_float4(0.f, 0.f, 0.f, 0.f);
}

// zero AH rows that edge_mlp will NOT fully overwrite with plain stores
__global__ __launch_bounds__(256) void k_zero_need(
    const int* __restrict__ histj, const int* __restrict__ basej,
    float* __restrict__ AH)
{
    int col = threadIdx.x & 127, sub = threadIdx.x >> 7;
    for (int d = blockIdx.x * 2 + sub; d < NNn; d += gridDim.x * 2) {
        int c = histj[d];
        bool need;
        if (c == 0) need = true;
        else {
            int b = basej[d], e = b + c;
            need = ((b & 63) == 0) || ((e & 63) == 0) || ((b >> 6) != ((e - 1) >> 6));
        }
        if (need) AH[(size_t)d * 128 + col] = 0.f;
    }
}

// ---------------- weight prep: f32 [K][128] -> f16 transposed [128][K] ----------------
__global__ __launch_bounds__(256) void k_wprep_big(
    const float* __restrict__ W011, const float* __restrict__ W012,
    _Float16* __restrict__ dst)
{
    int idx = blockIdx.x * 256 + threadIdx.x;        // 262144
    int which = idx >> 17;
    int r = idx & 131071;
    int n = r >> 10, k = r & 1023;
    const float* src = which ? W012 : W011;
    dst[idx] = (_Float16)src[k * 128 + n];
}

struct WSmall { const float* p[14]; };

__global__ __launch_bounds__(256) void k_wprep_small(WSmall ws, _Float16* __restrict__ dst)
{
    int idx = blockIdx.x * 256 + threadIdx.x;        // 14*16384 = 229376
    int seg = idx >> 14;
    int r = idx & 16383;
    int n = r >> 7, k = r & 127;
    const float* src = ws.p[seg];
    float v = src[k * 128 + n];
    if (seg < 12 && (seg % 3) == 0) v -= src[16384 + k * 128 + n];  // W1diff
    dst[idx] = (_Float16)v;
}

// ---------------- counting sort phase 1: per-dst histogram per mask ----------------
__global__ __launch_bounds__(256) void k_hist(
    const int* __restrict__ attr, const int* __restrict__ edst,
    int* __restrict__ hist)
{
    int e = blockIdx.x * 256 + threadIdx.x;
    int a = attr[e], d = edst[e];
    bool m[6]; eval_masks(a, m);
#pragma unroll
    for (int j = 0; j < 6; ++j)
        if (m[j]) atomicAdd(&hist[j * NNn + d], 1);
}

// ---------------- hierarchical exclusive scan ----------------
__global__ __launch_bounds__(256) void k_scan_a(
    const int* __restrict__ hist, int* __restrict__ base, int* __restrict__ bsum)
{
    __shared__ int wsum[4];
    int bid = blockIdx.x;
    int idx = bid * 256 + threadIdx.x;
    int tid = threadIdx.x, lane = tid & 63, wv = tid >> 6;
    int v = hist[idx];
    int x = v;
#pragma unroll
    for (int off = 1; off < 64; off <<= 1) {
        int y = __shfl_up(x, off, 64);
        if (lane >= off) x += y;
    }
    if (lane == 63) wsum[wv] = x;
    __syncthreads();
    int add = 0;
    for (int w = 0; w < wv; ++w) add += wsum[w];
    base[idx] = add + x - v;
    if (tid == 255) bsum[bid] = add + x;
}

__global__ __launch_bounds__(384) void k_scan_b(int* __restrict__ bsum, int* __restrict__ cnts)
{
    int wv = threadIdx.x >> 6;
    int lane = threadIdx.x & 63;
    int run = 0;
#pragma unroll
    for (int c0 = 0; c0 < 128; c0 += 64) {
        int v = bsum[wv * 128 + c0 + lane];
        int x = v;
#pragma unroll
        for (int off = 1; off < 64; off <<= 1) {
            int y = __shfl_up(x, off, 64);
            if (lane >= off) x += y;
        }
        bsum[wv * 128 + c0 + lane] = run + (x - v);
        run += __shfl(x, 63, 64);
    }
    if (lane == 0) cnts[wv] = run;
}

__global__ __launch_bounds__(256) void k_scan_c(int* __restrict__ base, const int* __restrict__ bsum)
{
    base[blockIdx.x * 256 + threadIdx.x] += bsum[blockIdx.x];
}

// ---------------- fill sorted lists ----------------
__global__ __launch_bounds__(256) void k_fill(
    const int* __restrict__ esrc, const int* __restrict__ edst,
    const int* __restrict__ attr, const int* __restrict__ base,
    int* __restrict__ fill, int2* __restrict__ arena)
{
    int e = blockIdx.x * 256 + threadIdx.x;
    int a = attr[e];
    int s = esrc[e], d = edst[e];
    bool m[6]; eval_masks(a, m);
    const int caps[6] = {CAP0, CAP1, CAP2, CAP3, CAP4, CAP5};
    const int offs[6] = {0, CAP0, CAP0+CAP1, CAP0+CAP1+CAP2,
                         CAP0+CAP1+CAP2+CAP3, CAP0+CAP1+CAP2+CAP3+CAP4};
#pragma unroll
    for (int j = 0; j < 6; ++j) {
        if (m[j]) {
            int pos = base[j * NNn + d] + atomicAdd(&fill[j * NNn + d], 1);
            if (pos < caps[j]) arena[offs[j] + pos] = make_int2(s, d);
        }
    }
}

// ---------------- fused input projection v2: 64 rows/block, aliased epilogue slab ----------------
// X = [xv@W011+b011 ; xa@W012+b012]; 512 blocks x 256 threads.
__global__ __launch_bounds__(256) void k_proj(
    const float* __restrict__ xv, const float* __restrict__ xa,
    const _Float16* __restrict__ BTv, const _Float16* __restrict__ BTa,
    const float* __restrict__ bv_, const float* __restrict__ ba_,
    float* __restrict__ X)
{
    __shared__ _Float16 Bl[128][136];          // 34816 B; epilogue slab aliases this
    __shared__ float bb[128];
    const int tid = threadIdx.x, wave = tid >> 6, lane = tid & 63;
    const int blk = blockIdx.x;
    const float* A; const _Float16* BT; const float* bias; int mbase, obase;
    if (blk < 384) { A = xv; BT = BTv; bias = bv_; mbase = blk * 64; obase = mbase; }
    else { A = xa; BT = BTa; bias = ba_; mbase = (blk - 384) * 64; obase = 24576 + mbase; }
    if (tid < 128) bb[tid] = bias[tid];

    const int mrow = mbase + wave * 16 + (lane & 15);
    const int fk   = (lane >> 4) * 8;
    f32x4 acc[8];
#pragma unroll
    for (int i = 0; i < 8; ++i) acc[i] = (f32x4){0,0,0,0};

    // prefetch A fragments for chunk 0
    f16x8 af[4];
#pragma unroll
    for (int t4 = 0; t4 < 4; ++t4) {
        const float* asrc = A + (size_t)mrow * 1024 + t4 * 32 + fk;
        float4 a0 = *(const float4*)asrc;
        float4 a1 = *(const float4*)(asrc + 4);
        af[t4] = (f16x8){ (_Float16)a0.x, (_Float16)a0.y, (_Float16)a0.z, (_Float16)a0.w,
                          (_Float16)a1.x, (_Float16)a1.y, (_Float16)a1.z, (_Float16)a1.w };
    }

    for (int kc = 0; kc < 8; ++kc) {
        __syncthreads();                       // Bl free (prev chunk MFMAs done)
#pragma unroll
        for (int it = 0; it < 8; ++it) {
            int c = it * 256 + tid;            // 2048 chunks of 8
            int n = c >> 4, koff = (c & 15) * 8;
            *(f16x8*)&Bl[n][koff] = *(const f16x8*)(BT + (size_t)n * 1024 + kc * 128 + koff);
        }
        __syncthreads();
        // prefetch next chunk's A fragments (overlaps with MFMAs below)
        f16x8 nf[4];
        if (kc < 7) {
#pragma unroll
            for (int t4 = 0; t4 < 4; ++t4) {
                const float* asrc = A + (size_t)mrow * 1024 + (kc + 1) * 128 + t4 * 32 + fk;
                float4 a0 = *(const float4*)asrc;
                float4 a1 = *(const float4*)(asrc + 4);
                nf[t4] = (f16x8){ (_Float16)a0.x, (_Float16)a0.y, (_Float16)a0.z, (_Float16)a0.w,
                                  (_Float16)a1.x, (_Float16)a1.y, (_Float16)a1.z, (_Float16)a1.w };
            }
        }
#pragma unroll
        for (int t4 = 0; t4 < 4; ++t4)
#pragma unroll
            for (int nt = 0; nt < 8; ++nt) {
                f16x8 bf = *(const f16x8*)&Bl[nt * 16 + (lane & 15)][t4 * 32 + fk];
                acc[nt] = __builtin_amdgcn_mfma_f32_16x16x32_f16(af[t4], bf, acc[nt], 0, 0, 0);
            }
#pragma unroll
        for (int t4 = 0; t4 < 4; ++t4) af[t4] = nf[t4];
    }
    __syncthreads();                           // all Bl reads done; alias as epilogue slab
    float* Hsf = (float*)&Bl[0][0] + (size_t)wave * 16 * 132;   // per-wave [16][132]
    const int cbase = lane & 15, rloc = (lane >> 4) * 4;
#pragma unroll
    for (int nt = 0; nt < 8; ++nt) {
        int c2 = nt * 16 + cbase;
        float bvv = bb[c2];
#pragma unroll
        for (int rr = 0; rr < 4; ++rr)
            Hsf[(rloc + rr) * 132 + c2] = acc[nt][rr] + bvv;
    }
#pragma unroll
    for (int it = 0; it < 8; ++it) {
        int id = it * 64 + lane;               // 512 float4 chunks per wave slab
        int row = id >> 5, off = (id & 31) * 4;
        float4 v = *(float4*)&Hsf[row * 132 + off];
        *(float4*)&X[(size_t)(obase + wave * 16 + row) * 128 + off] = v;
    }
}

// ---------------- PV GEMM v2: 64 rows/block, aliased epilogue slab ----------------
// P = A@BT1^T + b1 (f16), V = A@BT2^T (f16). 512 blocks x 256 threads.
__global__ __launch_bounds__(256) void k_pv(
    const float* __restrict__ A,
    const _Float16* __restrict__ BT1, const float* __restrict__ b1,
    const _Float16* __restrict__ BT2,
    _Float16* __restrict__ P, _Float16* __restrict__ V)
{
    __shared__ _Float16 Bl1[128][136];         // 34816 B; epilogue slab aliases this
    __shared__ _Float16 Bl2[128][136];
    __shared__ float bb[128];
    const int tid = threadIdx.x, wave = tid >> 6, lane = tid & 63;
    const int r0 = blockIdx.x * 64 + wave * 16;

    const int fk = (lane >> 4) * 8;
    const int mrow = blockIdx.x * 64 + wave * 16 + (lane & 15);
    // issue A loads first (overlap with B staging)
    float4 a0[4], a1[4];
#pragma unroll
    for (int t4 = 0; t4 < 4; ++t4) {
        const float* asrc = A + (size_t)mrow * 128 + t4 * 32 + fk;
        a0[t4] = *(const float4*)asrc;
        a1[t4] = *(const float4*)(asrc + 4);
    }
#pragma unroll
    for (int it = 0; it < 8; ++it) {
        int c = it * 256 + tid;                // 2048 chunks of 8 per matrix
        int n = c >> 4, koff = (c & 15) * 8;
        *(f16x8*)&Bl1[n][koff] = *(const f16x8*)(BT1 + (size_t)n * 128 + koff);
        *(f16x8*)&Bl2[n][koff] = *(const f16x8*)(BT2 + (size_t)n * 128 + koff);
    }
    if (tid < 128) bb[tid] = b1[tid];
    __syncthreads();

    f16x8 af[4];
#pragma unroll
    for (int t4 = 0; t4 < 4; ++t4)
        af[t4] = (f16x8){ (_Float16)a0[t4].x, (_Float16)a0[t4].y, (_Float16)a0[t4].z, (_Float16)a0[t4].w,
                          (_Float16)a1[t4].x, (_Float16)a1[t4].y, (_Float16)a1[t4].z, (_Float16)a1[t4].w };
    f32x4 acc1[8], acc2[8];
#pragma unroll
    for (int i = 0; i < 8; ++i) { acc1[i] = (f32x4){0,0,0,0}; acc2[i] = (f32x4){0,0,0,0}; }
#pragma unroll
    for (int t4 = 0; t4 < 4; ++t4)
#pragma unroll
        for (int nt = 0; nt < 8; ++nt) {
            f16x8 bf1 = *(const f16x8*)&Bl1[nt * 16 + (lane & 15)][t4 * 32 + fk];
            f16x8 bf2 = *(const f16x8*)&Bl2[nt * 16 + (lane & 15)][t4 * 32 + fk];
            acc1[nt] = __builtin_amdgcn_mfma_f32_16x16x32_f16(af[t4], bf1, acc1[nt], 0, 0, 0);
            acc2[nt] = __builtin_amdgcn_mfma_f32_16x16x32_f16(af[t4], bf2, acc2[nt], 0, 0, 0);
        }
    __syncthreads();                           // Bl1 reads done; alias as epilogue slab
    _Float16* Hs = &Bl1[0][0] + (size_t)wave * 16 * 136;   // per-wave [16][136]
    const int cbase = lane & 15, rloc = (lane >> 4) * 4;
#pragma unroll
    for (int nt = 0; nt < 8; ++nt) {
        int c2 = nt * 16 + cbase;
        float bvv = bb[c2];
#pragma unroll
        for (int rr = 0; rr < 4; ++rr)
            Hs[(rloc + rr) * 136 + c2] = (_Float16)(acc1[nt][rr] + bvv);
    }
#pragma unroll
    for (int it = 0; it < 4; ++it) {
        int id = it * 64 + lane;               // 256 f16x8 chunks per wave slab
        int row = id >> 4, koff = (id & 15) * 8;
        *(f16x8*)&P[(size_t)(r0 + row) * 128 + koff] = *(f16x8*)&Hs[row * 136 + koff];
    }
#pragma unroll
    for (int nt = 0; nt < 8; ++nt) {
        int c2 = nt * 16 + cbase;
#pragma unroll
        for (int rr = 0; rr < 4; ++rr)
            Hs[(rloc + rr) * 136 + c2] = (_Float16)acc2[nt][rr];
    }
#pragma unroll
    for (int it = 0; it < 4; ++it) {
        int id = it * 64 + lane;
        int row = id >> 4, koff = (id & 15) * 8;
        *(f16x8*)&V[(size_t)(r0 + row) * 128 + koff] = *(f16x8*)&Hs[row * 136 + koff];
    }
}

// ---------------- edge MLP on dst-sorted list (f16 P/V, vectorized gather) ----------------
__global__ __launch_bounds__(256, 3) void k_edge_mlp(
    const _Float16* __restrict__ P, const _Float16* __restrict__ V,
    const _Float16* __restrict__ W2T, const float* __restrict__ b2,
    const int2* __restrict__ list, const int* __restrict__ cntp, int cap,
    float* __restrict__ agg)
{
    __shared__ _Float16 Rl[64][136];
    __shared__ _Float16 W2l[128][136];
    __shared__ float b2l[128];
    __shared__ int2 eSD[64];
    __shared__ unsigned char gstart[66];
    __shared__ int gdst[64];
    __shared__ int ngrS;

    int cnt = min(*cntp, cap);
    int ntiles = (cnt + 63) >> 6;
    if ((int)blockIdx.x >= ntiles) return;

    const int tid  = threadIdx.x;
    const int wave = tid >> 6;
    const int lane = tid & 63;

#pragma unroll
    for (int i = 0; i < 8; ++i) {
        int c = tid + i * 256;
        int n = c >> 4, koff = (c & 15) * 8;
        *(f16x8*)&W2l[n][koff] = *(const f16x8*)(W2T + n * 128 + koff);
    }
    if (tid < 128) b2l[tid] = b2[tid];

    const int col   = tid & 127;
    const int half  = tid >> 7;
    const int frow  = wave * 16 + (lane & 15);
    const int fq    = (lane >> 4) * 8;
    const int rbase = wave * 16 + (lane >> 4) * 4;
    const int cbase = lane & 15;
    const int rrow  = tid >> 4;
    const int rch   = (tid & 15) * 8;

    for (int t = blockIdx.x; t < ntiles; t += gridDim.x) {
        __syncthreads();
        if (tid < 64) {
            int e = t * 64 + tid;
            eSD[tid] = (e < cnt) ? list[e] : make_int2(0, -1);
        }
        __syncthreads();
        if (tid < 64) {
            int d = eSD[tid].y;
            bool flag = (tid == 0) || (d != eSD[tid - 1].y);
            unsigned long long bm = __ballot(flag);
            int rank = (int)__popcll(bm & ((1ull << tid) - 1ull));
            if (flag) { gstart[rank] = (unsigned char)tid; gdst[rank] = d; }
            if (tid == 0) {
                int ng = (int)__popcll(bm);
                ngrS = ng;
                gstart[ng] = 64;
            }
        }
#pragma unroll
        for (int p = 0; p < 4; ++p) {
            int i = p * 16 + rrow;
            int2 sd = eSD[i];
            f16x8 rv = {0, 0, 0, 0, 0, 0, 0, 0};
            if (sd.y >= 0) {
                f16x8 pv = *(const f16x8*)(P + (size_t)sd.y * 128 + rch);
                f16x8 vv = *(const f16x8*)(V + (size_t)sd.x * 128 + rch);
                rv = pv + vv;
#pragma unroll
                for (int q = 0; q < 8; ++q)
                    rv[q] = (rv[q] > (_Float16)0.f) ? rv[q] : (_Float16)0.f;
            }
            *(f16x8*)&Rl[i][rch] = rv;
        }
        __syncthreads();

        f32x4 acc[8];
#pragma unroll
        for (int i = 0; i < 8; ++i) acc[i] = (f32x4){0,0,0,0};
#pragma unroll
        for (int t4 = 0; t4 < 4; ++t4) {
            f16x8 af = *(const f16x8*)&Rl[frow][t4 * 32 + fq];
#pragma unroll
            for (int nt = 0; nt < 8; ++nt) {
                f16x8 bf = *(const f16x8*)&W2l[nt * 16 + (lane & 15)][t4 * 32 + fq];
                acc[nt] = __builtin_amdgcn_mfma_f32_16x16x32_f16(af, bf, acc[nt], 0, 0, 0);
            }
        }
        __syncthreads();
#pragma unroll
        for (int nt = 0; nt < 8; ++nt) {
            int c2 = nt * 16 + cbase;
            float bv = b2l[c2];
#pragma unroll
            for (int rr = 0; rr < 4; ++rr)
                Rl[rbase + rr][c2] = (_Float16)fmaxf(acc[nt][rr] + bv, 0.f);
        }
        __syncthreads();
        int ng = ngrS;
        for (int g = half; g < ng; g += 2) {
            int s = gstart[g], e = gstart[g + 1];
            int d = gdst[g];
            if (d < 0) continue;
            float m = 0.f;
            for (int i = s; i < e; ++i)
                m = fmaxf(m, (float)Rl[i][col]);
            size_t o = (size_t)d * 128 + col;
            if (s == 0 || e == 64)
                atomicMax((unsigned int*)&agg[o], __float_as_uint(m));
            else
                agg[o] = m;
        }
    }
}

// ---------------- CSR gather-reduce kernels ----------------
__global__ __launch_bounds__(256) void k_csr_vpa(
    const float* __restrict__ X, const int2* __restrict__ list,
    const int* __restrict__ base, const int* __restrict__ cntarr, int cap,
    float* __restrict__ S)
{
    int col = threadIdx.x & 127;
    int sub = threadIdx.x >> 7;
    for (int d = blockIdx.x * 2 + sub; d < NNn; d += gridDim.x * 2) {
        int c = cntarr[d];
        float v = 0.f;
        if (c > 0) {
            int b = base[d];
            int end = min(b + c, cap);
            float mx = -3.0e38f;
            for (int i = b; i < end; ++i)
                mx = fmaxf(mx, X[(size_t)list[i].x * 128 + col]);
            v = fmaxf(X[(size_t)d * 128 + col] + mx, 0.f);
        }
        S[(size_t)d * 128 + col] = v;
    }
}

__global__ __launch_bounds__(256) void k_csr_acv(
    const float* __restrict__ X, const float* __restrict__ ares,
    const int2* __restrict__ list,
    const int* __restrict__ base, const int* __restrict__ cntarr, int cap,
    float* __restrict__ S)
{
    int col = threadIdx.x & 127;
    int sub = threadIdx.x >> 7;
    for (int d = blockIdx.x * 2 + sub; d < NNn; d += gridDim.x * 2) {
        int c = cntarr[d];
        float v = 0.f;
        if (c > 0) {
            int b = base[d];
            int end = min(b + c, cap);
            float s = 0.f;
            for (int i = b; i < end; ++i) {
                int sr = list[i].x;
                s += ares[sr] * X[(size_t)sr * 128 + col];
            }
            v = fmaxf(s + (float)c * X[(size_t)d * 128 + col], 0.f);
        }
        S[(size_t)d * 128 + col] = v;
    }
}

__global__ __launch_bounds__(256) void k_csr_meanc(
    const float* __restrict__ AH, const int2* __restrict__ list,
    const int* __restrict__ basej, const int* __restrict__ histj, int cap,
    const int* __restrict__ spk, int ntarg,
    float* __restrict__ S1c, float* __restrict__ AHc)
{
    int col = threadIdx.x & 127;
    int sub = threadIdx.x >> 7;
    int step = spk[0] * TT;
    for (int ci = blockIdx.x * 2 + sub; ci < ntarg; ci += gridDim.x * 2) {
        int d = (ci >> 7) * step + (ci & 127);
        int c = histj[d];
        float v = 0.f;
        if (c > 0) {
            int b = basej[d];
            int end = min(b + c, cap);
            float s = 0.f;
            for (int i = b; i < end; ++i)
                s += AH[(size_t)list[i].x * 128 + col];
            v = s / (float)c;
        }
        S1c[(size_t)ci * 128 + col] = v;
        AHc[(size_t)ci * 128 + col] = AH[(size_t)d * 128 + col];
    }
}

// ---------------- fc: a_res = a @ fc_W + fc_b ----------------
__global__ __launch_bounds__(256) void k_fc(
    const float* __restrict__ A, const float* __restrict__ W,
    const float* __restrict__ b, float* __restrict__ ares)
{
    int node = blockIdx.x * 4 + (threadIdx.x >> 6);
    int lane = threadIdx.x & 63;
    const float* row = A + (size_t)node * 128;
    float v = row[lane] * W[lane] + row[lane + 64] * W[lane + 64];
#pragma unroll
    for (int off = 32; off > 0; off >>= 1) v += __shfl_down(v, off, 64);
    if (lane == 0) ares[node] = v + b[0];
}

// ---------------- fused SAGE output: d_out = sum_b relu(S1c_b@Wl + AHc_b@Wr + bl) ----------------
__global__ __launch_bounds__(256) void k_sage_out(
    const float* __restrict__ S1c, const float* __restrict__ AHc,
    const _Float16* __restrict__ WlT, const _Float16* __restrict__ WrT,
    const float* __restrict__ bl, float* __restrict__ out, int ntarg)
{
    __shared__ _Float16 Al[64][40];
    __shared__ _Float16 Bl[128][40];
    const int tid  = threadIdx.x;
    const int wave = tid >> 6;
    const int lane = tid & 63;
    const int m0   = blockIdx.x * 64;

    f32x4 accB[8], accO[8];
#pragma unroll
    for (int i = 0; i < 8; ++i) { accB[i] = (f32x4){0,0,0,0}; accO[i] = (f32x4){0,0,0,0}; }

    const int ar = tid >> 2;
    const int ak = (tid & 3) * 8;
    const int fr = wave * 16 + (lane & 15);
    const int fk = (lane >> 4) * 8;
    const int rbase = wave * 16 + (lane >> 4) * 4;
    const int cbase = lane & 15;

    for (int seg = 0; seg < 6; ++seg) {
        int b = seg >> 1, which = seg & 1;
        const float* A = (which ? AHc : S1c) + (size_t)b * ntarg * 128;
        const _Float16* BT = which ? WrT : WlT;
        for (int k0 = 0; k0 < 128; k0 += 32) {
            __syncthreads();
            const float* asrc = A + (size_t)(m0 + ar) * 128 + (k0 + ak);
            float4 a0 = *(const float4*)asrc;
            float4 a1 = *(const float4*)(asrc + 4);
            f16x8 av = { (_Float16)a0.x, (_Float16)a0.y, (_Float16)a0.z, (_Float16)a0.w,
                         (_Float16)a1.x, (_Float16)a1.y, (_Float16)a1.z, (_Float16)a1.w };
            *(f16x8*)&Al[ar][ak] = av;
#pragma unroll
            for (int i = 0; i < 2; ++i) {
                int c = tid + i * 256;
                int n = c >> 2, koff = (c & 3) * 8;
                *(f16x8*)&Bl[n][koff] = *(const f16x8*)(BT + (size_t)n * 128 + k0 + koff);
            }
            __syncthreads();
            f16x8 af = *(const f16x8*)&Al[fr][fk];
#pragma unroll
            for (int nt = 0; nt < 8; ++nt) {
                f16x8 bf = *(const f16x8*)&Bl[nt * 16 + (lane & 15)][fk];
                accB[nt] = __builtin_amdgcn_mfma_f32_16x16x32_f16(af, bf, accB[nt], 0, 0, 0);
            }
        }
        if (which) {
#pragma unroll
            for (int nt = 0; nt < 8; ++nt) {
                int col = nt * 16 + cbase;
                float bv = bl[col];
#pragma unroll
                for (int rr = 0; rr < 4; ++rr) {
                    accO[nt][rr] += fmaxf(accB[nt][rr] + bv, 0.f);
                    accB[nt][rr] = 0.f;
                }
            }
        }
    }
#pragma unroll
    for (int nt = 0; nt < 8; ++nt) {
        int col = nt * 16 + cbase;
#pragma unroll
        for (int rr = 0; rr < 4; ++rr)
            out[(size_t)(m0 + rbase + rr) * 128 + col] = accO[nt][rr];
    }
}

extern "C" void kernel_launch(void* const* d_in, const int* in_sizes, int n_in,
                              void* d_out, int out_size, void* d_ws, size_t ws_size,
                              hipStream_t stream)
{
    (void)in_sizes; (void)n_in; (void)ws_size;
    const float* xv   = (const float*)d_in[0];
    const float* xa   = (const float*)d_in[1];
    const float* W011 = (const float*)d_in[2];
    const float* b011 = (const float*)d_in[3];
    const float* W012 = (const float*)d_in[4];
    const float* b012 = (const float*)d_in[5];
    const float* ecW1[4] = {(const float*)d_in[6],  (const float*)d_in[10],
                            (const float*)d_in[14], (const float*)d_in[18]};
    const float* ecb1[4] = {(const float*)d_in[7],  (const float*)d_in[11],
                            (const float*)d_in[15], (const float*)d_in[19]};
    const float* ecW2[4] = {(const float*)d_in[8],  (const float*)d_in[12],
                            (const float*)d_in[16], (const float*)d_in[20]};
    const float* ecb2[4] = {(const float*)d_in[9],  (const float*)d_in[13],
                            (const float*)d_in[17], (const float*)d_in[21]};
    const float* sageWl = (const float*)d_in[22];
    const float* sagebl = (const float*)d_in[23];
    const float* sageWr = (const float*)d_in[24];
    const float* fcW    = (const float*)d_in[25];
    const float* fcb    = (const float*)d_in[26];
    const int*   esrc   = (const int*)d_in[27];
    const int*   edst   = esrc + EEe;
    const int*   attr   = (const int*)d_in[28];
    const int*   spk    = (const int*)d_in[29];
    float* out = (float*)d_out;
    const int ntarg = out_size >> 7;       // 8192 target nodes

    const size_t NC = (size_t)NNn * CCc;   // 4194304
    float* ws   = (float*)d_ws;
    float* X    = ws;                      // [N,C] f32
    float* S1   = ws + 1 * NC;             // vpa out (full N); later S1c[3] compact
    float* AH   = ws + 2 * NC;             // edge-mlp aggregate
    float* XV2  = ws + 3 * NC;
    float* AHc  = ws + 4 * NC;             // compact AH snapshots [3][ntarg][C]
    _Float16* P16 = (_Float16*)(ws + 5 * NC);        // NC f16
    _Float16* V16 = P16 + NC;                        // NC f16
    float* ARES = ws + 6 * NC;             // 32768
    int*   cnts = (int*)(ARES + NNn);      // 16 ints
    int*   bsum = cnts + 16;               // 768 + pad
    int*   hist = bsum + 1024;             // 6*32768
    int*   fill = hist + 6 * NNn;          // 6*32768
    int*   base = fill + 6 * NNn;          // 6*32768
    int2*  arena = (int2*)(base + 6 * NNn);
    _Float16* WT = (_Float16*)(arena + ARENA_TOTAL);

    const int offs[6] = {0, CAP0, CAP0+CAP1, CAP0+CAP1+CAP2,
                         CAP0+CAP1+CAP2+CAP3, CAP0+CAP1+CAP2+CAP3+CAP4};
    const int caps[6] = {CAP0, CAP1, CAP2, CAP3, CAP4, CAP5};

    const _Float16* W011T = WT;
    const _Float16* W012T = WT + 131072;
    const _Float16* WTs   = WT + 262144;
    const _Float16* WlT   = WTs + 12 * 16384;
    const _Float16* WrT   = WTs + 13 * 16384;

    // ---- weight prep + counting-sort CSR build ----
    k_wprep_big<<<1024, 256, 0, stream>>>(W011, W012, WT);
    WSmall wsm;
    for (int i = 0; i < 4; ++i) {
        wsm.p[3*i + 0] = ecW1[i];
        wsm.p[3*i + 1] = ecW1[i] + 16384;
        wsm.p[3*i + 2] = ecW2[i];
    }
    wsm.p[12] = sageWl; wsm.p[13] = sageWr;
    k_wprep_small<<<896, 256, 0, stream>>>(wsm, (_Float16*)WTs);
    k_zero<<<(2 * 6 * NNn) / 1024, 256, 0, stream>>>((float*)hist);  // hist + fill
    k_hist<<<EEe / 256, 256, 0, stream>>>(attr, edst, hist);
    k_scan_a<<<768, 256, 0, stream>>>(hist, base, bsum);
    k_scan_b<<<1, 384, 0, stream>>>(bsum, cnts);
    k_scan_c<<<768, 256, 0, stream>>>(base, bsum);
    k_fill<<<EEe / 256, 256, 0, stream>>>(esrc, edst, attr, base, fill, arena);

    // ---- fused input projection ----
    k_proj<<<512, 256, 0, stream>>>(xv, xa, W011T, W012T, b011, b012, X);
    // ---- xa_g (mask 0) ----
    k_csr_vpa<<<2048, 256, 0, stream>>>(X, arena + offs[0], base + 0 * NNn,
                                        hist + 0 * NNn, caps[0], S1);
    // ---- EdgeConv A (mask 1): P/V f16 ----
    k_pv<<<512, 256, 0, stream>>>(S1, WTs, ecb1[0], WTs + 16384, P16, V16);
    k_zero_need<<<2048, 256, 0, stream>>>(hist + 1 * NNn, base + 1 * NNn, AH);
    k_edge_mlp<<<2048, 256, 0, stream>>>(P16, V16, WTs + 2 * 16384, ecb2[0],
                                         arena + offs[1], cnts + 1, caps[1], AH);
    k_fc<<<NNn / 4, 256, 0, stream>>>(AH, fcW, fcb, ARES);
    // ---- xv2 (mask 2) ----
    k_csr_acv<<<2048, 256, 0, stream>>>(X, ARES, arena + offs[2], base + 2 * NNn,
                                        hist + 2 * NNn, caps[2], XV2);
    // ---- three branches ----
    for (int b = 0; b < 3; ++b) {
        int j = 3 + b;
        const _Float16* Wd = WTs + (3 * (b + 1)) * 16384;
        k_pv<<<512, 256, 0, stream>>>(XV2, Wd, ecb1[b + 1], Wd + 16384, P16, V16);
        k_zero_need<<<2048, 256, 0, stream>>>(hist + j * NNn, base + j * NNn, AH);
        k_edge_mlp<<<2048, 256, 0, stream>>>(P16, V16, Wd + 2 * 16384, ecb2[b + 1],
                                             arena + offs[j], cnts + j, caps[j], AH);
        k_csr_meanc<<<2048, 256, 0, stream>>>(AH, arena + offs[j], base + j * NNn,
                                              hist + j * NNn, caps[j], spk, ntarg,
                                              S1 + (size_t)b * ntarg * 128,
                                              AHc + (size_t)b * ntarg * 128);
    }
    // ---- fused SAGE epilogue -> d_out ----
    k_sage_out<<<ntarg / 64, 256, 0, stream>>>(S1, AHc, WlT, WrT, sagebl, out, ntarg);
}

// Round 10
// 559.891 us; speedup vs baseline: 1.0153x; 1.0153x over previous
//
#include <hip/hip_runtime.h>
#include <cstdint>
#include <cstddef>

#define NVv 192
#define NAa 64
#define TT 128
#define FDd 1024
#define CCc 128
#define EEe 262144
#define NNn 32768

typedef _Float16 f16x8 __attribute__((ext_vector_type(8)));
typedef float f32x4 __attribute__((ext_vector_type(4)));

// list arena capacities/offsets (int2 units): vpa, aud, acv, m1, m2, m3
#define CAP0 65536
#define CAP1 65536
#define CAP2 65536
#define CAP3 98304
#define CAP4 98304
#define CAP5 147456
#define ARENA_TOTAL (CAP0+CAP1+CAP2+CAP3+CAP4+CAP5)   // 540672

__device__ __forceinline__ void eval_masks(int a, bool m[6]) {
    m[0] = (a == -3); m[1] = (a == -2); m[2] = (a == 3);
    m[3] = (a >= 0) & (a <= 1);
    m[4] = (a >= -1) & (a <= 0);
    m[5] = (a >= -1) & (a <= 1);
}

// ---------------- zero fill (1024 floats / block) ----------------
__global__ __launch_bounds__(256) void k_zero(float* __restrict__ p) {
    size_t i = (size_t)blockIdx.x * 1024 + (size_t)threadIdx.x * 4;
    *(float4*)(p + i) = make_float4(0.f, 0.f, 0.f, 0.f);
}

// zero AH rows that edge_mlp will NOT fully overwrite with plain stores
__global__ __launch_bounds__(256) void k_zero_need(
    const int* __restrict__ histj, const int* __restrict__ basej,
    float* __restrict__ AH)
{
    int col = threadIdx.x & 127, sub = threadIdx.x >> 7;
    for (int d = blockIdx.x * 2 + sub; d < NNn; d += gridDim.x * 2) {
        int c = histj[d];
        bool need;
        if (c == 0) need = true;
        else {
            int b = basej[d], e = b + c;
            need = ((b & 63) == 0) || ((e & 63) == 0) || ((b >> 6) != ((e - 1) >> 6));
        }
        if (need) AH[(size_t)d * 128 + col] = 0.f;
    }
}

// ---------------- weight prep: f32 [K][128] -> f16 transposed [128][K] ----------------
__global__ __launch_bounds__(256) void k_wprep_big(
    const float* __restrict__ W011, const float* __restrict__ W012,
    _Float16* __restrict__ dst)
{
    int idx = blockIdx.x * 256 + threadIdx.x;        // 262144
    int which = idx >> 17;
    int r = idx & 131071;
    int n = r >> 10, k = r & 1023;
    const float* src = which ? W012 : W011;
    dst[idx] = (_Float16)src[k * 128 + n];
}

struct WSmall { const float* p[14]; };

__global__ __launch_bounds__(256) void k_wprep_small(WSmall ws, _Float16* __restrict__ dst)
{
    int idx = blockIdx.x * 256 + threadIdx.x;        // 14*16384 = 229376
    int seg = idx >> 14;
    int r = idx & 16383;
    int n = r >> 7, k = r & 127;
    const float* src = ws.p[seg];
    float v = src[k * 128 + n];
    if (seg < 12 && (seg % 3) == 0) v -= src[16384 + k * 128 + n];  // W1diff
    dst[idx] = (_Float16)v;
}

// ---------------- counting sort phase 1: per-dst histogram per mask ----------------
__global__ __launch_bounds__(256) void k_hist(
    const int* __restrict__ attr, const int* __restrict__ edst,
    int* __restrict__ hist)
{
    int e = blockIdx.x * 256 + threadIdx.x;
    int a = attr[e], d = edst[e];
    bool m[6]; eval_masks(a, m);
#pragma unroll
    for (int j = 0; j < 6; ++j)
        if (m[j]) atomicAdd(&hist[j * NNn + d], 1);
}

// ---------------- hierarchical exclusive scan ----------------
__global__ __launch_bounds__(256) void k_scan_a(
    const int* __restrict__ hist, int* __restrict__ base, int* __restrict__ bsum)
{
    __shared__ int wsum[4];
    int bid = blockIdx.x;
    int idx = bid * 256 + threadIdx.x;
    int tid = threadIdx.x, lane = tid & 63, wv = tid >> 6;
    int v = hist[idx];
    int x = v;
#pragma unroll
    for (int off = 1; off < 64; off <<= 1) {
        int y = __shfl_up(x, off, 64);
        if (lane >= off) x += y;
    }
    if (lane == 63) wsum[wv] = x;
    __syncthreads();
    int add = 0;
    for (int w = 0; w < wv; ++w) add += wsum[w];
    base[idx] = add + x - v;
    if (tid == 255) bsum[bid] = add + x;
}

__global__ __launch_bounds__(384) void k_scan_b(int* __restrict__ bsum, int* __restrict__ cnts)
{
    int wv = threadIdx.x >> 6;
    int lane = threadIdx.x & 63;
    int run = 0;
#pragma unroll
    for (int c0 = 0; c0 < 128; c0 += 64) {
        int v = bsum[wv * 128 + c0 + lane];
        int x = v;
#pragma unroll
        for (int off = 1; off < 64; off <<= 1) {
            int y = __shfl_up(x, off, 64);
            if (lane >= off) x += y;
        }
        bsum[wv * 128 + c0 + lane] = run + (x - v);
        run += __shfl(x, 63, 64);
    }
    if (lane == 0) cnts[wv] = run;
}

__global__ __launch_bounds__(256) void k_scan_c(int* __restrict__ base, const int* __restrict__ bsum)
{
    base[blockIdx.x * 256 + threadIdx.x] += bsum[blockIdx.x];
}

// ---------------- fill sorted lists ----------------
__global__ __launch_bounds__(256) void k_fill(
    const int* __restrict__ esrc, const int* __restrict__ edst,
    const int* __restrict__ attr, const int* __restrict__ base,
    int* __restrict__ fill, int2* __restrict__ arena)
{
    int e = blockIdx.x * 256 + threadIdx.x;
    int a = attr[e];
    int s = esrc[e], d = edst[e];
    bool m[6]; eval_masks(a, m);
    const int caps[6] = {CAP0, CAP1, CAP2, CAP3, CAP4, CAP5};
    const int offs[6] = {0, CAP0, CAP0+CAP1, CAP0+CAP1+CAP2,
                         CAP0+CAP1+CAP2+CAP3, CAP0+CAP1+CAP2+CAP3+CAP4};
#pragma unroll
    for (int j = 0; j < 6; ++j) {
        if (m[j]) {
            int pos = base[j * NNn + d] + atomicAdd(&fill[j * NNn + d], 1);
            if (pos < caps[j]) arena[offs[j] + pos] = make_int2(s, d);
        }
    }
}

// ---------------- input projection v3: split-K (2 K-halves), 128 rows/block, 512 thr ----------------
// 512 blocks = 256 row-tiles x 2 K-halves; partials (no bias) -> Pp0/Pp1.
__global__ __launch_bounds__(512) void k_proj(
    const float* __restrict__ xv, const float* __restrict__ xa,
    const _Float16* __restrict__ BTv, const _Float16* __restrict__ BTa,
    float* __restrict__ Pp0, float* __restrict__ Pp1)
{
    __shared__ _Float16 Bl[128][136];          // 34816 B; epilogue slab aliases this
    const int tid = threadIdx.x, wave = tid >> 6, lane = tid & 63;
    const int tile = blockIdx.x >> 1, kh = blockIdx.x & 1;
    const float* A; const _Float16* BT; int mbase, obase;
    if (tile < 192) { A = xv; BT = BTv; mbase = tile * 128; obase = mbase; }
    else { A = xa; BT = BTa; mbase = (tile - 192) * 128; obase = 24576 + mbase; }
    float* Pout = kh ? Pp1 : Pp0;
    const int kbase = kh * 512;

    const int mrow = mbase + wave * 16 + (lane & 15);
    const int fk   = (lane >> 4) * 8;
    f32x4 acc[8];
#pragma unroll
    for (int i = 0; i < 8; ++i) acc[i] = (f32x4){0,0,0,0};

    // prefetch A fragments for chunk 0
    f16x8 af[4];
#pragma unroll
    for (int t4 = 0; t4 < 4; ++t4) {
        const float* asrc = A + (size_t)mrow * 1024 + kbase + t4 * 32 + fk;
        float4 a0 = *(const float4*)asrc;
        float4 a1 = *(const float4*)(asrc + 4);
        af[t4] = (f16x8){ (_Float16)a0.x, (_Float16)a0.y, (_Float16)a0.z, (_Float16)a0.w,
                          (_Float16)a1.x, (_Float16)a1.y, (_Float16)a1.z, (_Float16)a1.w };
    }

    for (int kc = 0; kc < 4; ++kc) {
        __syncthreads();                       // Bl free (prev chunk MFMAs done)
#pragma unroll
        for (int it = 0; it < 4; ++it) {
            int c = it * 512 + tid;            // 2048 chunks of 8
            int n = c >> 4, koff = (c & 15) * 8;
            *(f16x8*)&Bl[n][koff] =
                *(const f16x8*)(BT + (size_t)n * 1024 + kbase + kc * 128 + koff);
        }
        __syncthreads();
        f16x8 nf[4];
        if (kc < 3) {
#pragma unroll
            for (int t4 = 0; t4 < 4; ++t4) {
                const float* asrc = A + (size_t)mrow * 1024 + kbase + (kc + 1) * 128 + t4 * 32 + fk;
                float4 a0 = *(const float4*)asrc;
                float4 a1 = *(const float4*)(asrc + 4);
                nf[t4] = (f16x8){ (_Float16)a0.x, (_Float16)a0.y, (_Float16)a0.z, (_Float16)a0.w,
                                  (_Float16)a1.x, (_Float16)a1.y, (_Float16)a1.z, (_Float16)a1.w };
            }
        }
#pragma unroll
        for (int t4 = 0; t4 < 4; ++t4)
#pragma unroll
            for (int nt = 0; nt < 8; ++nt) {
                f16x8 bf = *(const f16x8*)&Bl[nt * 16 + (lane & 15)][t4 * 32 + fk];
                acc[nt] = __builtin_amdgcn_mfma_f32_16x16x32_f16(af[t4], bf, acc[nt], 0, 0, 0);
            }
#pragma unroll
        for (int t4 = 0; t4 < 4; ++t4) af[t4] = nf[t4];
    }
    __syncthreads();                           // all Bl reads done; alias as epilogue slab
    const int cbase = lane & 15, rloc = (lane >> 4) * 4;
    const int wgrp = wave & 3;
    float* Hsf = (float*)&Bl[0][0] + (size_t)wgrp * 16 * 132;   // 4 wave-slabs fit in Bl
#pragma unroll
    for (int grp = 0; grp < 2; ++grp) {
        if ((wave >> 2) == grp) {
#pragma unroll
            for (int nt = 0; nt < 8; ++nt) {
                int c2 = nt * 16 + cbase;
#pragma unroll
                for (int rr = 0; rr < 4; ++rr)
                    Hsf[(rloc + rr) * 132 + c2] = acc[nt][rr];
            }
#pragma unroll
            for (int it = 0; it < 8; ++it) {
                int id = it * 64 + lane;
                int row = id >> 5, off = (id & 31) * 4;
                float4 v = *(float4*)&Hsf[row * 132 + off];
                *(float4*)&Pout[(size_t)(obase + wave * 16 + row) * 128 + off] = v;
            }
        }
        __syncthreads();
    }
}

// ---------------- reduce: X = Pp0 + Pp1 + bias(row) ----------------
__global__ __launch_bounds__(256) void k_reduce(
    const float* __restrict__ Pp0, const float* __restrict__ Pp1,
    const float* __restrict__ b011, const float* __restrict__ b012,
    float* __restrict__ X)
{
    size_t f = (size_t)blockIdx.x * 256 + threadIdx.x;   // float4 index
    size_t i = f * 4;
    int col = (int)(i & 127);
    int row = (int)(i >> 7);
    const float* bias = (row < 24576) ? b011 : b012;
    float4 a = *(const float4*)(Pp0 + i);
    float4 b = *(const float4*)(Pp1 + i);
    float4 bb = *(const float4*)(bias + col);
    float4 o = make_float4(a.x + b.x + bb.x, a.y + b.y + bb.y,
                           a.z + b.z + bb.z, a.w + b.w + bb.w);
    *(float4*)(X + i) = o;
}

// ---------------- PV GEMM v2: 64 rows/block, aliased epilogue slab ----------------
__global__ __launch_bounds__(256) void k_pv(
    const float* __restrict__ A,
    const _Float16* __restrict__ BT1, const float* __restrict__ b1,
    const _Float16* __restrict__ BT2,
    _Float16* __restrict__ P, _Float16* __restrict__ V)
{
    __shared__ _Float16 Bl1[128][136];
    __shared__ _Float16 Bl2[128][136];
    __shared__ float bb[128];
    const int tid = threadIdx.x, wave = tid >> 6, lane = tid & 63;
    const int r0 = blockIdx.x * 64 + wave * 16;

    const int fk = (lane >> 4) * 8;
    const int mrow = blockIdx.x * 64 + wave * 16 + (lane & 15);
    float4 a0[4], a1[4];
#pragma unroll
    for (int t4 = 0; t4 < 4; ++t4) {
        const float* asrc = A + (size_t)mrow * 128 + t4 * 32 + fk;
        a0[t4] = *(const float4*)asrc;
        a1[t4] = *(const float4*)(asrc + 4);
    }
#pragma unroll
    for (int it = 0; it < 8; ++it) {
        int c = it * 256 + tid;
        int n = c >> 4, koff = (c & 15) * 8;
        *(f16x8*)&Bl1[n][koff] = *(const f16x8*)(BT1 + (size_t)n * 128 + koff);
        *(f16x8*)&Bl2[n][koff] = *(const f16x8*)(BT2 + (size_t)n * 128 + koff);
    }
    if (tid < 128) bb[tid] = b1[tid];
    __syncthreads();

    f16x8 af[4];
#pragma unroll
    for (int t4 = 0; t4 < 4; ++t4)
        af[t4] = (f16x8){ (_Float16)a0[t4].x, (_Float16)a0[t4].y, (_Float16)a0[t4].z, (_Float16)a0[t4].w,
                          (_Float16)a1[t4].x, (_Float16)a1[t4].y, (_Float16)a1[t4].z, (_Float16)a1[t4].w };
    f32x4 acc1[8], acc2[8];
#pragma unroll
    for (int i = 0; i < 8; ++i) { acc1[i] = (f32x4){0,0,0,0}; acc2[i] = (f32x4){0,0,0,0}; }
#pragma unroll
    for (int t4 = 0; t4 < 4; ++t4)
#pragma unroll
        for (int nt = 0; nt < 8; ++nt) {
            f16x8 bf1 = *(const f16x8*)&Bl1[nt * 16 + (lane & 15)][t4 * 32 + fk];
            f16x8 bf2 = *(const f16x8*)&Bl2[nt * 16 + (lane & 15)][t4 * 32 + fk];
            acc1[nt] = __builtin_amdgcn_mfma_f32_16x16x32_f16(af[t4], bf1, acc1[nt], 0, 0, 0);
            acc2[nt] = __builtin_amdgcn_mfma_f32_16x16x32_f16(af[t4], bf2, acc2[nt], 0, 0, 0);
        }
    __syncthreads();                           // Bl1 reads done; alias as epilogue slab
    _Float16* Hs = &Bl1[0][0] + (size_t)wave * 16 * 136;
    const int cbase = lane & 15, rloc = (lane >> 4) * 4;
#pragma unroll
    for (int nt = 0; nt < 8; ++nt) {
        int c2 = nt * 16 + cbase;
        float bvv = bb[c2];
#pragma unroll
        for (int rr = 0; rr < 4; ++rr)
            Hs[(rloc + rr) * 136 + c2] = (_Float16)(acc1[nt][rr] + bvv);
    }
#pragma unroll
    for (int it = 0; it < 4; ++it) {
        int id = it * 64 + lane;
        int row = id >> 4, koff = (id & 15) * 8;
        *(f16x8*)&P[(size_t)(r0 + row) * 128 + koff] = *(f16x8*)&Hs[row * 136 + koff];
    }
#pragma unroll
    for (int nt = 0; nt < 8; ++nt) {
        int c2 = nt * 16 + cbase;
#pragma unroll
        for (int rr = 0; rr < 4; ++rr)
            Hs[(rloc + rr) * 136 + c2] = (_Float16)acc2[nt][rr];
    }
#pragma unroll
    for (int it = 0; it < 4; ++it) {
        int id = it * 64 + lane;
        int row = id >> 4, koff = (id & 15) * 8;
        *(f16x8*)&V[(size_t)(r0 + row) * 128 + koff] = *(f16x8*)&Hs[row * 136 + koff];
    }
}

// ---------------- edge MLP on dst-sorted list (f16 P/V, vectorized gather) ----------------
__global__ __launch_bounds__(256, 3) void k_edge_mlp(
    const _Float16* __restrict__ P, const _Float16* __restrict__ V,
    const _Float16* __restrict__ W2T, const float* __restrict__ b2,
    const int2* __restrict__ list, const int* __restrict__ cntp, int cap,
    float* __restrict__ agg)
{
    __shared__ _Float16 Rl[64][136];
    __shared__ _Float16 W2l[128][136];
    __shared__ float b2l[128];
    __shared__ int2 eSD[64];
    __shared__ unsigned char gstart[66];
    __shared__ int gdst[64];
    __shared__ int ngrS;

    int cnt = min(*cntp, cap);
    int ntiles = (cnt + 63) >> 6;
    if ((int)blockIdx.x >= ntiles) return;

    const int tid  = threadIdx.x;
    const int wave = tid >> 6;
    const int lane = tid & 63;

#pragma unroll
    for (int i = 0; i < 8; ++i) {
        int c = tid + i * 256;
        int n = c >> 4, koff = (c & 15) * 8;
        *(f16x8*)&W2l[n][koff] = *(const f16x8*)(W2T + n * 128 + koff);
    }
    if (tid < 128) b2l[tid] = b2[tid];

    const int col   = tid & 127;
    const int half  = tid >> 7;
    const int frow  = wave * 16 + (lane & 15);
    const int fq    = (lane >> 4) * 8;
    const int rbase = wave * 16 + (lane >> 4) * 4;
    const int cbase = lane & 15;
    const int rrow  = tid >> 4;
    const int rch   = (tid & 15) * 8;

    for (int t = blockIdx.x; t < ntiles; t += gridDim.x) {
        __syncthreads();
        if (tid < 64) {
            int e = t * 64 + tid;
            eSD[tid] = (e < cnt) ? list[e] : make_int2(0, -1);
        }
        __syncthreads();
        if (tid < 64) {
            int d = eSD[tid].y;
            bool flag = (tid == 0) || (d != eSD[tid - 1].y);
            unsigned long long bm = __ballot(flag);
            int rank = (int)__popcll(bm & ((1ull << tid) - 1ull));
            if (flag) { gstart[rank] = (unsigned char)tid; gdst[rank] = d; }
            if (tid == 0) {
                int ng = (int)__popcll(bm);
                ngrS = ng;
                gstart[ng] = 64;
            }
        }
#pragma unroll
        for (int p = 0; p < 4; ++p) {
            int i = p * 16 + rrow;
            int2 sd = eSD[i];
            f16x8 rv = {0, 0, 0, 0, 0, 0, 0, 0};
            if (sd.y >= 0) {
                f16x8 pv = *(const f16x8*)(P + (size_t)sd.y * 128 + rch);
                f16x8 vv = *(const f16x8*)(V + (size_t)sd.x * 128 + rch);
                rv = pv + vv;
#pragma unroll
                for (int q = 0; q < 8; ++q)
                    rv[q] = (rv[q] > (_Float16)0.f) ? rv[q] : (_Float16)0.f;
            }
            *(f16x8*)&Rl[i][rch] = rv;
        }
        __syncthreads();

        f32x4 acc[8];
#pragma unroll
        for (int i = 0; i < 8; ++i) acc[i] = (f32x4){0,0,0,0};
#pragma unroll
        for (int t4 = 0; t4 < 4; ++t4) {
            f16x8 af = *(const f16x8*)&Rl[frow][t4 * 32 + fq];
#pragma unroll
            for (int nt = 0; nt < 8; ++nt) {
                f16x8 bf = *(const f16x8*)&W2l[nt * 16 + (lane & 15)][t4 * 32 + fq];
                acc[nt] = __builtin_amdgcn_mfma_f32_16x16x32_f16(af, bf, acc[nt], 0, 0, 0);
            }
        }
        __syncthreads();
#pragma unroll
        for (int nt = 0; nt < 8; ++nt) {
            int c2 = nt * 16 + cbase;
            float bv = b2l[c2];
#pragma unroll
            for (int rr = 0; rr < 4; ++rr)
                Rl[rbase + rr][c2] = (_Float16)fmaxf(acc[nt][rr] + bv, 0.f);
        }
        __syncthreads();
        int ng = ngrS;
        for (int g = half; g < ng; g += 2) {
            int s = gstart[g], e = gstart[g + 1];
            int d = gdst[g];
            if (d < 0) continue;
            float m = 0.f;
            for (int i = s; i < e; ++i)
                m = fmaxf(m, (float)Rl[i][col]);
            size_t o = (size_t)d * 128 + col;
            if (s == 0 || e == 64)
                atomicMax((unsigned int*)&agg[o], __float_as_uint(m));
            else
                agg[o] = m;
        }
    }
}

// ---------------- CSR gather-reduce kernels ----------------
__global__ __launch_bounds__(256) void k_csr_vpa(
    const float* __restrict__ X, const int2* __restrict__ list,
    const int* __restrict__ base, const int* __restrict__ cntarr, int cap,
    float* __restrict__ S)
{
    int col = threadIdx.x & 127;
    int sub = threadIdx.x >> 7;
    for (int d = blockIdx.x * 2 + sub; d < NNn; d += gridDim.x * 2) {
        int c = cntarr[d];
        float v = 0.f;
        if (c > 0) {
            int b = base[d];
            int end = min(b + c, cap);
            float mx = -3.0e38f;
            for (int i = b; i < end; ++i)
                mx = fmaxf(mx, X[(size_t)list[i].x * 128 + col]);
            v = fmaxf(X[(size_t)d * 128 + col] + mx, 0.f);
        }
        S[(size_t)d * 128 + col] = v;
    }
}

__global__ __launch_bounds__(256) void k_csr_acv(
    const float* __restrict__ X, const float* __restrict__ ares,
    const int2* __restrict__ list,
    const int* __restrict__ base, const int* __restrict__ cntarr, int cap,
    float* __restrict__ S)
{
    int col = threadIdx.x & 127;
    int sub = threadIdx.x >> 7;
    for (int d = blockIdx.x * 2 + sub; d < NNn; d += gridDim.x * 2) {
        int c = cntarr[d];
        float v = 0.f;
        if (c > 0) {
            int b = base[d];
            int end = min(b + c, cap);
            float s = 0.f;
            for (int i = b; i < end; ++i) {
                int sr = list[i].x;
                s += ares[sr] * X[(size_t)sr * 128 + col];
            }
            v = fmaxf(s + (float)c * X[(size_t)d * 128 + col], 0.f);
        }
        S[(size_t)d * 128 + col] = v;
    }
}

__global__ __launch_bounds__(256) void k_csr_meanc(
    const float* __restrict__ AH, const int2* __restrict__ list,
    const int* __restrict__ basej, const int* __restrict__ histj, int cap,
    const int* __restrict__ spk, int ntarg,
    float* __restrict__ S1c, float* __restrict__ AHc)
{
    int col = threadIdx.x & 127;
    int sub = threadIdx.x >> 7;
    int step = spk[0] * TT;
    for (int ci = blockIdx.x * 2 + sub; ci < ntarg; ci += gridDim.x * 2) {
        int d = (ci >> 7) * step + (ci & 127);
        int c = histj[d];
        float v = 0.f;
        if (c > 0) {
            int b = basej[d];
            int end = min(b + c, cap);
            float s = 0.f;
            for (int i = b; i < end; ++i)
                s += AH[(size_t)list[i].x * 128 + col];
            v = s / (float)c;
        }
        S1c[(size_t)ci * 128 + col] = v;
        AHc[(size_t)ci * 128 + col] = AH[(size_t)d * 128 + col];
    }
}

// ---------------- fc: a_res = a @ fc_W + fc_b ----------------
__global__ __launch_bounds__(256) void k_fc(
    const float* __restrict__ A, const float* __restrict__ W,
    const float* __restrict__ b, float* __restrict__ ares)
{
    int node = blockIdx.x * 4 + (threadIdx.x >> 6);
    int lane = threadIdx.x & 63;
    const float* row = A + (size_t)node * 128;
    float v = row[lane] * W[lane] + row[lane + 64] * W[lane + 64];
#pragma unroll
    for (int off = 32; off > 0; off >>= 1) v += __shfl_down(v, off, 64);
    if (lane == 0) ares[node] = v + b[0];
}

// ---------------- fused SAGE output: d_out = sum_b relu(S1c_b@Wl + AHc_b@Wr + bl) ----------------
__global__ __launch_bounds__(256) void k_sage_out(
    const float* __restrict__ S1c, const float* __restrict__ AHc,
    const _Float16* __restrict__ WlT, const _Float16* __restrict__ WrT,
    const float* __restrict__ bl, float* __restrict__ out, int ntarg)
{
    __shared__ _Float16 Al[64][40];
    __shared__ _Float16 Bl[128][40];
    const int tid  = threadIdx.x;
    const int wave = tid >> 6;
    const int lane = tid & 63;
    const int m0   = blockIdx.x * 64;

    f32x4 accB[8], accO[8];
#pragma unroll
    for (int i = 0; i < 8; ++i) { accB[i] = (f32x4){0,0,0,0}; accO[i] = (f32x4){0,0,0,0}; }

    const int ar = tid >> 2;
    const int ak = (tid & 3) * 8;
    const int fr = wave * 16 + (lane & 15);
    const int fk = (lane >> 4) * 8;
    const int rbase = wave * 16 + (lane >> 4) * 4;
    const int cbase = lane & 15;

    for (int seg = 0; seg < 6; ++seg) {
        int b = seg >> 1, which = seg & 1;
        const float* A = (which ? AHc : S1c) + (size_t)b * ntarg * 128;
        const _Float16* BT = which ? WrT : WlT;
        for (int k0 = 0; k0 < 128; k0 += 32) {
            __syncthreads();
            const float* asrc = A + (size_t)(m0 + ar) * 128 + (k0 + ak);
            float4 a0 = *(const float4*)asrc;
            float4 a1 = *(const float4*)(asrc + 4);
            f16x8 av = { (_Float16)a0.x, (_Float16)a0.y, (_Float16)a0.z, (_Float16)a0.w,
                         (_Float16)a1.x, (_Float16)a1.y, (_Float16)a1.z, (_Float16)a1.w };
            *(f16x8*)&Al[ar][ak] = av;
#pragma unroll
            for (int i = 0; i < 2; ++i) {
                int c = tid + i * 256;
                int n = c >> 2, koff = (c & 3) * 8;
                *(f16x8*)&Bl[n][koff] = *(const f16x8*)(BT + (size_t)n * 128 + k0 + koff);
            }
            __syncthreads();
            f16x8 af = *(const f16x8*)&Al[fr][fk];
#pragma unroll
            for (int nt = 0; nt < 8; ++nt) {
                f16x8 bf = *(const f16x8*)&Bl[nt * 16 + (lane & 15)][fk];
                accB[nt] = __builtin_amdgcn_mfma_f32_16x16x32_f16(af, bf, accB[nt], 0, 0, 0);
            }
        }
        if (which) {
#pragma unroll
            for (int nt = 0; nt < 8; ++nt) {
                int col = nt * 16 + cbase;
                float bv = bl[col];
#pragma unroll
                for (int rr = 0; rr < 4; ++rr) {
                    accO[nt][rr] += fmaxf(accB[nt][rr] + bv, 0.f);
                    accB[nt][rr] = 0.f;
                }
            }
        }
    }
#pragma unroll
    for (int nt = 0; nt < 8; ++nt) {
        int col = nt * 16 + cbase;
#pragma unroll
        for (int rr = 0; rr < 4; ++rr)
            out[(size_t)(m0 + rbase + rr) * 128 + col] = accO[nt][rr];
    }
}

extern "C" void kernel_launch(void* const* d_in, const int* in_sizes, int n_in,
                              void* d_out, int out_size, void* d_ws, size_t ws_size,
                              hipStream_t stream)
{
    (void)in_sizes; (void)n_in; (void)ws_size;
    const float* xv   = (const float*)d_in[0];
    const float* xa   = (const float*)d_in[1];
    const float* W011 = (const float*)d_in[2];
    const float* b011 = (const float*)d_in[3];
    const float* W012 = (const float*)d_in[4];
    const float* b012 = (const float*)d_in[5];
    const float* ecW1[4] = {(const float*)d_in[6],  (const float*)d_in[10],
                            (const float*)d_in[14], (const float*)d_in[18]};
    const float* ecb1[4] = {(const float*)d_in[7],  (const float*)d_in[11],
                            (const float*)d_in[15], (const float*)d_in[19]};
    const float* ecW2[4] = {(const float*)d_in[8],  (const float*)d_in[12],
                            (const float*)d_in[16], (const float*)d_in[20]};
    const float* ecb2[4] = {(const float*)d_in[9],  (const float*)d_in[13],
                            (const float*)d_in[17], (const float*)d_in[21]};
    const float* sageWl = (const float*)d_in[22];
    const float* sagebl = (const float*)d_in[23];
    const float* sageWr = (const float*)d_in[24];
    const float* fcW    = (const float*)d_in[25];
    const float* fcb    = (const float*)d_in[26];
    const int*   esrc   = (const int*)d_in[27];
    const int*   edst   = esrc + EEe;
    const int*   attr   = (const int*)d_in[28];
    const int*   spk    = (const int*)d_in[29];
    float* out = (float*)d_out;
    const int ntarg = out_size >> 7;       // 8192 target nodes

    const size_t NC = (size_t)NNn * CCc;   // 4194304
    float* ws   = (float*)d_ws;
    float* X    = ws;                      // [N,C] f32
    float* S1   = ws + 1 * NC;             // vpa out (full N); later S1c[3] compact
    float* AH   = ws + 2 * NC;             // edge-mlp aggregate; proj partial 1 before that
    float* XV2  = ws + 3 * NC;             // xv2; proj partial 0 before csr_acv
    float* AHc  = ws + 4 * NC;             // compact AH snapshots [3][ntarg][C]
    _Float16* P16 = (_Float16*)(ws + 5 * NC);        // NC f16
    _Float16* V16 = P16 + NC;                        // NC f16
    float* ARES = ws + 6 * NC;             // 32768
    int*   cnts = (int*)(ARES + NNn);      // 16 ints
    int*   bsum = cnts + 16;               // 768 + pad
    int*   hist = bsum + 1024;             // 6*32768
    int*   fill = hist + 6 * NNn;          // 6*32768
    int*   base = fill + 6 * NNn;          // 6*32768
    int2*  arena = (int2*)(base + 6 * NNn);
    _Float16* WT = (_Float16*)(arena + ARENA_TOTAL);

    const int offs[6] = {0, CAP0, CAP0+CAP1, CAP0+CAP1+CAP2,
                         CAP0+CAP1+CAP2+CAP3, CAP0+CAP1+CAP2+CAP3+CAP4};
    const int caps[6] = {CAP0, CAP1, CAP2, CAP3, CAP4, CAP5};

    const _Float16* W011T = WT;
    const _Float16* W012T = WT + 131072;
    const _Float16* WTs   = WT + 262144;
    const _Float16* WlT   = WTs + 12 * 16384;
    const _Float16* WrT   = WTs + 13 * 16384;

    // ---- weight prep + counting-sort CSR build ----
    k_wprep_big<<<1024, 256, 0, stream>>>(W011, W012, WT);
    WSmall wsm;
    for (int i = 0; i < 4; ++i) {
        wsm.p[3*i + 0] = ecW1[i];
        wsm.p[3*i + 1] = ecW1[i] + 16384;
        wsm.p[3*i + 2] = ecW2[i];
    }
    wsm.p[12] = sageWl; wsm.p[13] = sageWr;
    k_wprep_small<<<896, 256, 0, stream>>>(wsm, (_Float16*)WTs);
    k_zero<<<(2 * 6 * NNn) / 1024, 256, 0, stream>>>((float*)hist);  // hist + fill
    k_hist<<<EEe / 256, 256, 0, stream>>>(attr, edst, hist);
    k_scan_a<<<768, 256, 0, stream>>>(hist, base, bsum);
    k_scan_b<<<1, 384, 0, stream>>>(bsum, cnts);
    k_scan_c<<<768, 256, 0, stream>>>(base, bsum);
    k_fill<<<EEe / 256, 256, 0, stream>>>(esrc, edst, attr, base, fill, arena);

    // ---- input projection: split-K partials (XV2/AH slots are free here) + reduce ----
    k_proj<<<512, 512, 0, stream>>>(xv, xa, W011T, W012T, XV2, AH);
    k_reduce<<<(int)(NC / 1024), 256, 0, stream>>>(XV2, AH, b011, b012, X);
    // ---- xa_g (mask 0) ----
    k_csr_vpa<<<2048, 256, 0, stream>>>(X, arena + offs[0], base + 0 * NNn,
                                        hist + 0 * NNn, caps[0], S1);
    // ---- EdgeConv A (mask 1): P/V f16 ----
    k_pv<<<512, 256, 0, stream>>>(S1, WTs, ecb1[0], WTs + 16384, P16, V16);
    k_zero_need<<<2048, 256, 0, stream>>>(hist + 1 * NNn, base + 1 * NNn, AH);
    k_edge_mlp<<<2048, 256, 0, stream>>>(P16, V16, WTs + 2 * 16384, ecb2[0],
                                         arena + offs[1], cnts + 1, caps[1], AH);
    k_fc<<<NNn / 4, 256, 0, stream>>>(AH, fcW, fcb, ARES);
    // ---- xv2 (mask 2) ----
    k_csr_acv<<<2048, 256, 0, stream>>>(X, ARES, arena + offs[2], base + 2 * NNn,
                                        hist + 2 * NNn, caps[2], XV2);
    // ---- three branches ----
    for (int b = 0; b < 3; ++b) {
        int j = 3 + b;
        const _Float16* Wd = WTs + (3 * (b + 1)) * 16384;
        k_pv<<<512, 256, 0, stream>>>(XV2, Wd, ecb1[b + 1], Wd + 16384, P16, V16);
        k_zero_need<<<2048, 256, 0, stream>>>(hist + j * NNn, base + j * NNn, AH);
        k_edge_mlp<<<2048, 256, 0, stream>>>(P16, V16, Wd + 2 * 16384, ecb2[b + 1],
                                             arena + offs[j], cnts + j, caps[j], AH);
        k_csr_meanc<<<2048, 256, 0, stream>>>(AH, arena + offs[j], base + j * NNn,
                                              hist + j * NNn, caps[j], spk, ntarg,
                                              S1 + (size_t)b * ntarg * 128,
                                              AHc + (size_t)b * ntarg * 128);
    }
    // ---- fused SAGE epilogue -> d_out ----
    k_sage_out<<<ntarg / 64, 256, 0, stream>>>(S1, AHc, WlT, WrT, sagebl, out, ntarg);
}

// Round 11
// 554.387 us; speedup vs baseline: 1.0254x; 1.0099x over previous
//
#include <hip/hip_runtime.h>
#include <cstdint>
#include <cstddef>

#define NVv 192
#define NAa 64
#define TT 128
#define FDd 1024
#define CCc 128
#define EEe 262144
#define NNn 32768

typedef _Float16 f16x8 __attribute__((ext_vector_type(8)));
typedef float f32x4 __attribute__((ext_vector_type(4)));

// list arena capacities/offsets (int2 units): vpa, aud, acv, m1, m2, m3
#define CAP0 65536
#define CAP1 65536
#define CAP2 65536
#define CAP3 98304
#define CAP4 98304
#define CAP5 147456
#define ARENA_TOTAL (CAP0+CAP1+CAP2+CAP3+CAP4+CAP5)   // 540672

__device__ __forceinline__ void eval_masks(int a, bool m[6]) {
    m[0] = (a == -3); m[1] = (a == -2); m[2] = (a == 3);
    m[3] = (a >= 0) & (a <= 1);
    m[4] = (a >= -1) & (a <= 0);
    m[5] = (a >= -1) & (a <= 1);
}

// ---------------- zero fill (1024 floats / block) ----------------
__global__ __launch_bounds__(256) void k_zero(float* __restrict__ p) {
    size_t i = (size_t)blockIdx.x * 1024 + (size_t)threadIdx.x * 4;
    *(float4*)(p + i) = make_float4(0.f, 0.f, 0.f, 0.f);
}

// fused: zero the atomicMax-path rows of all four AH buffers (masks 1,3,4,5)
__global__ __launch_bounds__(256) void k_zero4(
    const int* __restrict__ hist, const int* __restrict__ base,
    float* __restrict__ AH0, float* __restrict__ AH1,
    float* __restrict__ AH2, float* __restrict__ AH3)
{
    int col = threadIdx.x & 127, sub = threadIdx.x >> 7;
    const int js[4] = {1, 3, 4, 5};
    float* AHs[4] = {AH0, AH1, AH2, AH3};
    for (int d = blockIdx.x * 2 + sub; d < NNn; d += gridDim.x * 2) {
#pragma unroll
        for (int jj = 0; jj < 4; ++jj) {
            int j = js[jj];
            int c = hist[j * NNn + d];
            bool need;
            if (c == 0) need = true;
            else {
                int b = base[j * NNn + d], e = b + c;
                need = ((b & 63) == 0) || ((e & 63) == 0) || ((b >> 6) != ((e - 1) >> 6));
            }
            if (need) AHs[jj][(size_t)d * 128 + col] = 0.f;
        }
    }
}

// ---------------- weight prep: f32 [K][128] -> f16 transposed [128][K] ----------------
__global__ __launch_bounds__(256) void k_wprep_big(
    const float* __restrict__ W011, const float* __restrict__ W012,
    _Float16* __restrict__ dst)
{
    int idx = blockIdx.x * 256 + threadIdx.x;        // 262144
    int which = idx >> 17;
    int r = idx & 131071;
    int n = r >> 10, k = r & 1023;
    const float* src = which ? W012 : W011;
    dst[idx] = (_Float16)src[k * 128 + n];
}

struct WSmall { const float* p[14]; };

__global__ __launch_bounds__(256) void k_wprep_small(WSmall ws, _Float16* __restrict__ dst)
{
    int idx = blockIdx.x * 256 + threadIdx.x;        // 14*16384 = 229376
    int seg = idx >> 14;
    int r = idx & 16383;
    int n = r >> 7, k = r & 127;
    const float* src = ws.p[seg];
    float v = src[k * 128 + n];
    if (seg < 12 && (seg % 3) == 0) v -= src[16384 + k * 128 + n];  // W1diff
    dst[idx] = (_Float16)v;
}

// ---------------- counting sort phase 1: per-dst histogram per mask ----------------
__global__ __launch_bounds__(256) void k_hist(
    const int* __restrict__ attr, const int* __restrict__ edst,
    int* __restrict__ hist)
{
    int e = blockIdx.x * 256 + threadIdx.x;
    int a = attr[e], d = edst[e];
    bool m[6]; eval_masks(a, m);
#pragma unroll
    for (int j = 0; j < 6; ++j)
        if (m[j]) atomicAdd(&hist[j * NNn + d], 1);
}

// ---------------- hierarchical exclusive scan ----------------
__global__ __launch_bounds__(256) void k_scan_a(
    const int* __restrict__ hist, int* __restrict__ base, int* __restrict__ bsum)
{
    __shared__ int wsum[4];
    int bid = blockIdx.x;
    int idx = bid * 256 + threadIdx.x;
    int tid = threadIdx.x, lane = tid & 63, wv = tid >> 6;
    int v = hist[idx];
    int x = v;
#pragma unroll
    for (int off = 1; off < 64; off <<= 1) {
        int y = __shfl_up(x, off, 64);
        if (lane >= off) x += y;
    }
    if (lane == 63) wsum[wv] = x;
    __syncthreads();
    int add = 0;
    for (int w = 0; w < wv; ++w) add += wsum[w];
    base[idx] = add + x - v;
    if (tid == 255) bsum[bid] = add + x;
}

__global__ __launch_bounds__(384) void k_scan_b(int* __restrict__ bsum, int* __restrict__ cnts)
{
    int wv = threadIdx.x >> 6;
    int lane = threadIdx.x & 63;
    int run = 0;
#pragma unroll
    for (int c0 = 0; c0 < 128; c0 += 64) {
        int v = bsum[wv * 128 + c0 + lane];
        int x = v;
#pragma unroll
        for (int off = 1; off < 64; off <<= 1) {
            int y = __shfl_up(x, off, 64);
            if (lane >= off) x += y;
        }
        bsum[wv * 128 + c0 + lane] = run + (x - v);
        run += __shfl(x, 63, 64);
    }
    if (lane == 0) cnts[wv] = run;
}

__global__ __launch_bounds__(256) void k_scan_c(int* __restrict__ base, const int* __restrict__ bsum)
{
    base[blockIdx.x * 256 + threadIdx.x] += bsum[blockIdx.x];
}

// ---------------- fill sorted lists ----------------
__global__ __launch_bounds__(256) void k_fill(
    const int* __restrict__ esrc, const int* __restrict__ edst,
    const int* __restrict__ attr, const int* __restrict__ base,
    int* __restrict__ fill, int2* __restrict__ arena)
{
    int e = blockIdx.x * 256 + threadIdx.x;
    int a = attr[e];
    int s = esrc[e], d = edst[e];
    bool m[6]; eval_masks(a, m);
    const int caps[6] = {CAP0, CAP1, CAP2, CAP3, CAP4, CAP5};
    const int offs[6] = {0, CAP0, CAP0+CAP1, CAP0+CAP1+CAP2,
                         CAP0+CAP1+CAP2+CAP3, CAP0+CAP1+CAP2+CAP3+CAP4};
#pragma unroll
    for (int j = 0; j < 6; ++j) {
        if (m[j]) {
            int pos = base[j * NNn + d] + atomicAdd(&fill[j * NNn + d], 1);
            if (pos < caps[j]) arena[offs[j] + pos] = make_int2(s, d);
        }
    }
}

// ---------------- input projection v4: split-K + double-buffered B (1 barrier/chunk) ----------------
// 512 blocks = 256 row-tiles x 2 K-halves; partials (no bias) -> Pp0/Pp1.
__global__ __launch_bounds__(512) void k_proj(
    const float* __restrict__ xv, const float* __restrict__ xa,
    const _Float16* __restrict__ BTv, const _Float16* __restrict__ BTa,
    float* __restrict__ Pp0, float* __restrict__ Pp1)
{
    __shared__ _Float16 Bl[2][128][136];       // 69632 B; epilogue slab aliases Bl[0]
    const int tid = threadIdx.x, wave = tid >> 6, lane = tid & 63;
    const int tile = blockIdx.x >> 1, kh = blockIdx.x & 1;
    const float* A; const _Float16* BT; int mbase, obase;
    if (tile < 192) { A = xv; BT = BTv; mbase = tile * 128; obase = mbase; }
    else { A = xa; BT = BTa; mbase = (tile - 192) * 128; obase = 24576 + mbase; }
    float* Pout = kh ? Pp1 : Pp0;
    const int kbase = kh * 512;

    const int mrow = mbase + wave * 16 + (lane & 15);
    const int fk   = (lane >> 4) * 8;
    f32x4 acc[8];
#pragma unroll
    for (int i = 0; i < 8; ++i) acc[i] = (f32x4){0,0,0,0};

    // stage chunk 0 into Bl[0]
#pragma unroll
    for (int it = 0; it < 4; ++it) {
        int c = it * 512 + tid;                // 2048 chunks of 8
        int n = c >> 4, koff = (c & 15) * 8;
        *(f16x8*)&Bl[0][n][koff] = *(const f16x8*)(BT + (size_t)n * 1024 + kbase + koff);
    }
    // prefetch A fragments for chunk 0
    f16x8 af[4];
#pragma unroll
    for (int t4 = 0; t4 < 4; ++t4) {
        const float* asrc = A + (size_t)mrow * 1024 + kbase + t4 * 32 + fk;
        float4 a0 = *(const float4*)asrc;
        float4 a1 = *(const float4*)(asrc + 4);
        af[t4] = (f16x8){ (_Float16)a0.x, (_Float16)a0.y, (_Float16)a0.z, (_Float16)a0.w,
                          (_Float16)a1.x, (_Float16)a1.y, (_Float16)a1.z, (_Float16)a1.w };
    }
    __syncthreads();

    for (int kc = 0; kc < 4; ++kc) {
        const int cur = kc & 1;
        f16x8 nf[4];
        if (kc < 3) {
            const int nxt = cur ^ 1;
            // stage next chunk's B (overlaps this chunk's MFMAs; nxt's prior readers
            // finished before the barrier ending iteration kc-1)
#pragma unroll
            for (int it = 0; it < 4; ++it) {
                int c = it * 512 + tid;
                int n = c >> 4, koff = (c & 15) * 8;
                *(f16x8*)&Bl[nxt][n][koff] =
                    *(const f16x8*)(BT + (size_t)n * 1024 + kbase + (kc + 1) * 128 + koff);
            }
            // prefetch next chunk's A fragments
#pragma unroll
            for (int t4 = 0; t4 < 4; ++t4) {
                const float* asrc = A + (size_t)mrow * 1024 + kbase + (kc + 1) * 128 + t4 * 32 + fk;
                float4 a0 = *(const float4*)asrc;
                float4 a1 = *(const float4*)(asrc + 4);
                nf[t4] = (f16x8){ (_Float16)a0.x, (_Float16)a0.y, (_Float16)a0.z, (_Float16)a0.w,
                                  (_Float16)a1.x, (_Float16)a1.y, (_Float16)a1.z, (_Float16)a1.w };
            }
        }
#pragma unroll
        for (int t4 = 0; t4 < 4; ++t4)
#pragma unroll
            for (int nt = 0; nt < 8; ++nt) {
                f16x8 bf = *(const f16x8*)&Bl[cur][nt * 16 + (lane & 15)][t4 * 32 + fk];
                acc[nt] = __builtin_amdgcn_mfma_f32_16x16x32_f16(af[t4], bf, acc[nt], 0, 0, 0);
            }
        if (kc < 3) {
#pragma unroll
            for (int t4 = 0; t4 < 4; ++t4) af[t4] = nf[t4];
        }
        __syncthreads();                       // one barrier per chunk
    }
    // epilogue via aliased slab in Bl[0] (all reads drained by final barrier)
    const int cbase = lane & 15, rloc = (lane >> 4) * 4;
    const int wgrp = wave & 3;
    float* Hsf = (float*)&Bl[0][0][0] + (size_t)wgrp * 16 * 132;   // 4 wave-slabs
#pragma unroll
    for (int grp = 0; grp < 2; ++grp) {
        if ((wave >> 2) == grp) {
#pragma unroll
            for (int nt = 0; nt < 8; ++nt) {
                int c2 = nt * 16 + cbase;
#pragma unroll
                for (int rr = 0; rr < 4; ++rr)
                    Hsf[(rloc + rr) * 132 + c2] = acc[nt][rr];
            }
#pragma unroll
            for (int it = 0; it < 8; ++it) {
                int id = it * 64 + lane;
                int row = id >> 5, off = (id & 31) * 4;
                float4 v = *(float4*)&Hsf[row * 132 + off];
                *(float4*)&Pout[(size_t)(obase + wave * 16 + row) * 128 + off] = v;
            }
        }
        __syncthreads();
    }
}

// ---------------- reduce: X = Pp0 + Pp1 + bias(row) ----------------
__global__ __launch_bounds__(256) void k_reduce(
    const float* __restrict__ Pp0, const float* __restrict__ Pp1,
    const float* __restrict__ b011, const float* __restrict__ b012,
    float* __restrict__ X)
{
    size_t f = (size_t)blockIdx.x * 256 + threadIdx.x;   // float4 index
    size_t i = f * 4;
    int col = (int)(i & 127);
    int row = (int)(i >> 7);
    const float* bias = (row < 24576) ? b011 : b012;
    float4 a = *(const float4*)(Pp0 + i);
    float4 b = *(const float4*)(Pp1 + i);
    float4 bb = *(const float4*)(bias + col);
    float4 o = make_float4(a.x + b.x + bb.x, a.y + b.y + bb.y,
                           a.z + b.z + bb.z, a.w + b.w + bb.w);
    *(float4*)(X + i) = o;
}

// ---------------- PV GEMM: 64 rows/block, aliased epilogue slab ----------------
__global__ __launch_bounds__(256) void k_pv(
    const float* __restrict__ A,
    const _Float16* __restrict__ BT1, const float* __restrict__ b1,
    const _Float16* __restrict__ BT2,
    _Float16* __restrict__ P, _Float16* __restrict__ V)
{
    __shared__ _Float16 Bl1[128][136];
    __shared__ _Float16 Bl2[128][136];
    __shared__ float bb[128];
    const int tid = threadIdx.x, wave = tid >> 6, lane = tid & 63;
    const int r0 = blockIdx.x * 64 + wave * 16;

    const int fk = (lane >> 4) * 8;
    const int mrow = blockIdx.x * 64 + wave * 16 + (lane & 15);
    float4 a0[4], a1[4];
#pragma unroll
    for (int t4 = 0; t4 < 4; ++t4) {
        const float* asrc = A + (size_t)mrow * 128 + t4 * 32 + fk;
        a0[t4] = *(const float4*)asrc;
        a1[t4] = *(const float4*)(asrc + 4);
    }
#pragma unroll
    for (int it = 0; it < 8; ++it) {
        int c = it * 256 + tid;
        int n = c >> 4, koff = (c & 15) * 8;
        *(f16x8*)&Bl1[n][koff] = *(const f16x8*)(BT1 + (size_t)n * 128 + koff);
        *(f16x8*)&Bl2[n][koff] = *(const f16x8*)(BT2 + (size_t)n * 128 + koff);
    }
    if (tid < 128) bb[tid] = b1[tid];
    __syncthreads();

    f16x8 af[4];
#pragma unroll
    for (int t4 = 0; t4 < 4; ++t4)
        af[t4] = (f16x8){ (_Float16)a0[t4].x, (_Float16)a0[t4].y, (_Float16)a0[t4].z, (_Float16)a0[t4].w,
                          (_Float16)a1[t4].x, (_Float16)a1[t4].y, (_Float16)a1[t4].z, (_Float16)a1[t4].w };
    f32x4 acc1[8], acc2[8];
#pragma unroll
    for (int i = 0; i < 8; ++i) { acc1[i] = (f32x4){0,0,0,0}; acc2[i] = (f32x4){0,0,0,0}; }
#pragma unroll
    for (int t4 = 0; t4 < 4; ++t4)
#pragma unroll
        for (int nt = 0; nt < 8; ++nt) {
            f16x8 bf1 = *(const f16x8*)&Bl1[nt * 16 + (lane & 15)][t4 * 32 + fk];
            f16x8 bf2 = *(const f16x8*)&Bl2[nt * 16 + (lane & 15)][t4 * 32 + fk];
            acc1[nt] = __builtin_amdgcn_mfma_f32_16x16x32_f16(af[t4], bf1, acc1[nt], 0, 0, 0);
            acc2[nt] = __builtin_amdgcn_mfma_f32_16x16x32_f16(af[t4], bf2, acc2[nt], 0, 0, 0);
        }
    __syncthreads();                           // Bl1 reads done; alias as epilogue slab
    _Float16* Hs = &Bl1[0][0] + (size_t)wave * 16 * 136;
    const int cbase = lane & 15, rloc = (lane >> 4) * 4;
#pragma unroll
    for (int nt = 0; nt < 8; ++nt) {
        int c2 = nt * 16 + cbase;
        float bvv = bb[c2];
#pragma unroll
        for (int rr = 0; rr < 4; ++rr)
            Hs[(rloc + rr) * 136 + c2] = (_Float16)(acc1[nt][rr] + bvv);
    }
#pragma unroll
    for (int it = 0; it < 4; ++it) {
        int id = it * 64 + lane;
        int row = id >> 4, koff = (id & 15) * 8;
        *(f16x8*)&P[(size_t)(r0 + row) * 128 + koff] = *(f16x8*)&Hs[row * 136 + koff];
    }
#pragma unroll
    for (int nt = 0; nt < 8; ++nt) {
        int c2 = nt * 16 + cbase;
#pragma unroll
        for (int rr = 0; rr < 4; ++rr)
            Hs[(rloc + rr) * 136 + c2] = (_Float16)acc2[nt][rr];
    }
#pragma unroll
    for (int it = 0; it < 4; ++it) {
        int id = it * 64 + lane;
        int row = id >> 4, koff = (id & 15) * 8;
        *(f16x8*)&V[(size_t)(r0 + row) * 128 + koff] = *(f16x8*)&Hs[row * 136 + koff];
    }
}

// ---------------- edge MLP on dst-sorted list (f16 P/V, vectorized gather) ----------------
__global__ __launch_bounds__(256, 3) void k_edge_mlp(
    const _Float16* __restrict__ P, const _Float16* __restrict__ V,
    const _Float16* __restrict__ W2T, const float* __restrict__ b2,
    const int2* __restrict__ list, const int* __restrict__ cntp, int cap,
    float* __restrict__ agg)
{
    __shared__ _Float16 Rl[64][136];
    __shared__ _Float16 W2l[128][136];
    __shared__ float b2l[128];
    __shared__ int2 eSD[64];
    __shared__ unsigned char gstart[66];
    __shared__ int gdst[64];
    __shared__ int ngrS;

    int cnt = min(*cntp, cap);
    int ntiles = (cnt + 63) >> 6;
    if ((int)blockIdx.x >= ntiles) return;

    const int tid  = threadIdx.x;
    const int wave = tid >> 6;
    const int lane = tid & 63;

#pragma unroll
    for (int i = 0; i < 8; ++i) {
        int c = tid + i * 256;
        int n = c >> 4, koff = (c & 15) * 8;
        *(f16x8*)&W2l[n][koff] = *(const f16x8*)(W2T + n * 128 + koff);
    }
    if (tid < 128) b2l[tid] = b2[tid];

    const int col   = tid & 127;
    const int half  = tid >> 7;
    const int frow  = wave * 16 + (lane & 15);
    const int fq    = (lane >> 4) * 8;
    const int rbase = wave * 16 + (lane >> 4) * 4;
    const int cbase = lane & 15;
    const int rrow  = tid >> 4;
    const int rch   = (tid & 15) * 8;

    for (int t = blockIdx.x; t < ntiles; t += gridDim.x) {
        __syncthreads();
        if (tid < 64) {
            int e = t * 64 + tid;
            eSD[tid] = (e < cnt) ? list[e] : make_int2(0, -1);
        }
        __syncthreads();
        if (tid < 64) {
            int d = eSD[tid].y;
            bool flag = (tid == 0) || (d != eSD[tid - 1].y);
            unsigned long long bm = __ballot(flag);
            int rank = (int)__popcll(bm & ((1ull << tid) - 1ull));
            if (flag) { gstart[rank] = (unsigned char)tid; gdst[rank] = d; }
            if (tid == 0) {
                int ng = (int)__popcll(bm);
                ngrS = ng;
                gstart[ng] = 64;
            }
        }
#pragma unroll
        for (int p = 0; p < 4; ++p) {
            int i = p * 16 + rrow;
            int2 sd = eSD[i];
            f16x8 rv = {0, 0, 0, 0, 0, 0, 0, 0};
            if (sd.y >= 0) {
                f16x8 pv = *(const f16x8*)(P + (size_t)sd.y * 128 + rch);
                f16x8 vv = *(const f16x8*)(V + (size_t)sd.x * 128 + rch);
                rv = pv + vv;
#pragma unroll
                for (int q = 0; q < 8; ++q)
                    rv[q] = (rv[q] > (_Float16)0.f) ? rv[q] : (_Float16)0.f;
            }
            *(f16x8*)&Rl[i][rch] = rv;
        }
        __syncthreads();

        f32x4 acc[8];
#pragma unroll
        for (int i = 0; i < 8; ++i) acc[i] = (f32x4){0,0,0,0};
#pragma unroll
        for (int t4 = 0; t4 < 4; ++t4) {
            f16x8 af = *(const f16x8*)&Rl[frow][t4 * 32 + fq];
#pragma unroll
            for (int nt = 0; nt < 8; ++nt) {
                f16x8 bf = *(const f16x8*)&W2l[nt * 16 + (lane & 15)][t4 * 32 + fq];
                acc[nt] = __builtin_amdgcn_mfma_f32_16x16x32_f16(af, bf, acc[nt], 0, 0, 0);
            }
        }
        __syncthreads();
#pragma unroll
        for (int nt = 0; nt < 8; ++nt) {
            int c2 = nt * 16 + cbase;
            float bv = b2l[c2];
#pragma unroll
            for (int rr = 0; rr < 4; ++rr)
                Rl[rbase + rr][c2] = (_Float16)fmaxf(acc[nt][rr] + bv, 0.f);
        }
        __syncthreads();
        int ng = ngrS;
        for (int g = half; g < ng; g += 2) {
            int s = gstart[g], e = gstart[g + 1];
            int d = gdst[g];
            if (d < 0) continue;
            float m = 0.f;
            for (int i = s; i < e; ++i)
                m = fmaxf(m, (float)Rl[i][col]);
            size_t o = (size_t)d * 128 + col;
            if (s == 0 || e == 64)
                atomicMax((unsigned int*)&agg[o], __float_as_uint(m));
            else
                agg[o] = m;
        }
    }
}

// ---------------- CSR gather-reduce kernels ----------------
__global__ __launch_bounds__(256) void k_csr_vpa(
    const float* __restrict__ X, const int2* __restrict__ list,
    const int* __restrict__ base, const int* __restrict__ cntarr, int cap,
    float* __restrict__ S)
{
    int col = threadIdx.x & 127;
    int sub = threadIdx.x >> 7;
    for (int d = blockIdx.x * 2 + sub; d < NNn; d += gridDim.x * 2) {
        int c = cntarr[d];
        float v = 0.f;
        if (c > 0) {
            int b = base[d];
            int end = min(b + c, cap);
            float mx = -3.0e38f;
            for (int i = b; i < end; ++i)
                mx = fmaxf(mx, X[(size_t)list[i].x * 128 + col]);
            v = fmaxf(X[(size_t)d * 128 + col] + mx, 0.f);
        }
        S[(size_t)d * 128 + col] = v;
    }
}

__global__ __launch_bounds__(256) void k_csr_acv(
    const float* __restrict__ X, const float* __restrict__ ares,
    const int2* __restrict__ list,
    const int* __restrict__ base, const int* __restrict__ cntarr, int cap,
    float* __restrict__ S)
{
    int col = threadIdx.x & 127;
    int sub = threadIdx.x >> 7;
    for (int d = blockIdx.x * 2 + sub; d < NNn; d += gridDim.x * 2) {
        int c = cntarr[d];
        float v = 0.f;
        if (c > 0) {
            int b = base[d];
            int end = min(b + c, cap);
            float s = 0.f;
            for (int i = b; i < end; ++i) {
                int sr = list[i].x;
                s += ares[sr] * X[(size_t)sr * 128 + col];
            }
            v = fmaxf(s + (float)c * X[(size_t)d * 128 + col], 0.f);
        }
        S[(size_t)d * 128 + col] = v;
    }
}

__global__ __launch_bounds__(256) void k_csr_meanc(
    const float* __restrict__ AH, const int2* __restrict__ list,
    const int* __restrict__ basej, const int* __restrict__ histj, int cap,
    const int* __restrict__ spk, int ntarg,
    float* __restrict__ S1c, float* __restrict__ AHc)
{
    int col = threadIdx.x & 127;
    int sub = threadIdx.x >> 7;
    int step = spk[0] * TT;
    for (int ci = blockIdx.x * 2 + sub; ci < ntarg; ci += gridDim.x * 2) {
        int d = (ci >> 7) * step + (ci & 127);
        int c = histj[d];
        float v = 0.f;
        if (c > 0) {
            int b = basej[d];
            int end = min(b + c, cap);
            float s = 0.f;
            for (int i = b; i < end; ++i)
                s += AH[(size_t)list[i].x * 128 + col];
            v = s / (float)c;
        }
        S1c[(size_t)ci * 128 + col] = v;
        AHc[(size_t)ci * 128 + col] = AH[(size_t)d * 128 + col];
    }
}

// ---------------- fc: a_res = a @ fc_W + fc_b ----------------
__global__ __launch_bounds__(256) void k_fc(
    const float* __restrict__ A, const float* __restrict__ W,
    const float* __restrict__ b, float* __restrict__ ares)
{
    int node = blockIdx.x * 4 + (threadIdx.x >> 6);
    int lane = threadIdx.x & 63;
    const float* row = A + (size_t)node * 128;
    float v = row[lane] * W[lane] + row[lane + 64] * W[lane + 64];
#pragma unroll
    for (int off = 32; off > 0; off >>= 1) v += __shfl_down(v, off, 64);
    if (lane == 0) ares[node] = v + b[0];
}

// ---------------- fused SAGE output: d_out = sum_b relu(S1c_b@Wl + AHc_b@Wr + bl) ----------------
__global__ __launch_bounds__(256) void k_sage_out(
    const float* __restrict__ S1c, const float* __restrict__ AHc,
    const _Float16* __restrict__ WlT, const _Float16* __restrict__ WrT,
    const float* __restrict__ bl, float* __restrict__ out, int ntarg)
{
    __shared__ _Float16 Al[64][40];
    __shared__ _Float16 Bl[128][40];
    const int tid  = threadIdx.x;
    const int wave = tid >> 6;
    const int lane = tid & 63;
    const int m0   = blockIdx.x * 64;

    f32x4 accB[8], accO[8];
#pragma unroll
    for (int i = 0; i < 8; ++i) { accB[i] = (f32x4){0,0,0,0}; accO[i] = (f32x4){0,0,0,0}; }

    const int ar = tid >> 2;
    const int ak = (tid & 3) * 8;
    const int fr = wave * 16 + (lane & 15);
    const int fk = (lane >> 4) * 8;
    const int rbase = wave * 16 + (lane >> 4) * 4;
    const int cbase = lane & 15;

    for (int seg = 0; seg < 6; ++seg) {
        int b = seg >> 1, which = seg & 1;
        const float* A = (which ? AHc : S1c) + (size_t)b * ntarg * 128;
        const _Float16* BT = which ? WrT : WlT;
        for (int k0 = 0; k0 < 128; k0 += 32) {
            __syncthreads();
            const float* asrc = A + (size_t)(m0 + ar) * 128 + (k0 + ak);
            float4 a0 = *(const float4*)asrc;
            float4 a1 = *(const float4*)(asrc + 4);
            f16x8 av = { (_Float16)a0.x, (_Float16)a0.y, (_Float16)a0.z, (_Float16)a0.w,
                         (_Float16)a1.x, (_Float16)a1.y, (_Float16)a1.z, (_Float16)a1.w };
            *(f16x8*)&Al[ar][ak] = av;
#pragma unroll
            for (int i = 0; i < 2; ++i) {
                int c = tid + i * 256;
                int n = c >> 2, koff = (c & 3) * 8;
                *(f16x8*)&Bl[n][koff] = *(const f16x8*)(BT + (size_t)n * 128 + k0 + koff);
            }
            __syncthreads();
            f16x8 af = *(const f16x8*)&Al[fr][fk];
#pragma unroll
            for (int nt = 0; nt < 8; ++nt) {
                f16x8 bf = *(const f16x8*)&Bl[nt * 16 + (lane & 15)][fk];
                accB[nt] = __builtin_amdgcn_mfma_f32_16x16x32_f16(af, bf, accB[nt], 0, 0, 0);
            }
        }
        if (which) {
#pragma unroll
            for (int nt = 0; nt < 8; ++nt) {
                int col = nt * 16 + cbase;
                float bv = bl[col];
#pragma unroll
                for (int rr = 0; rr < 4; ++rr) {
                    accO[nt][rr] += fmaxf(accB[nt][rr] + bv, 0.f);
                    accB[nt][rr] = 0.f;
                }
            }
        }
    }
#pragma unroll
    for (int nt = 0; nt < 8; ++nt) {
        int col = nt * 16 + cbase;
#pragma unroll
        for (int rr = 0; rr < 4; ++rr)
            out[(size_t)(m0 + rbase + rr) * 128 + col] = accO[nt][rr];
    }
}

extern "C" void kernel_launch(void* const* d_in, const int* in_sizes, int n_in,
                              void* d_out, int out_size, void* d_ws, size_t ws_size,
                              hipStream_t stream)
{
    (void)in_sizes; (void)n_in; (void)ws_size;
    const float* xv   = (const float*)d_in[0];
    const float* xa   = (const float*)d_in[1];
    const float* W011 = (const float*)d_in[2];
    const float* b011 = (const float*)d_in[3];
    const float* W012 = (const float*)d_in[4];
    const float* b012 = (const float*)d_in[5];
    const float* ecW1[4] = {(const float*)d_in[6],  (const float*)d_in[10],
                            (const float*)d_in[14], (const float*)d_in[18]};
    const float* ecb1[4] = {(const float*)d_in[7],  (const float*)d_in[11],
                            (const float*)d_in[15], (const float*)d_in[19]};
    const float* ecW2[4] = {(const float*)d_in[8],  (const float*)d_in[12],
                            (const float*)d_in[16], (const float*)d_in[20]};
    const float* ecb2[4] = {(const float*)d_in[9],  (const float*)d_in[13],
                            (const float*)d_in[17], (const float*)d_in[21]};
    const float* sageWl = (const float*)d_in[22];
    const float* sagebl = (const float*)d_in[23];
    const float* sageWr = (const float*)d_in[24];
    const float* fcW    = (const float*)d_in[25];
    const float* fcb    = (const float*)d_in[26];
    const int*   esrc   = (const int*)d_in[27];
    const int*   edst   = esrc + EEe;
    const int*   attr   = (const int*)d_in[28];
    const int*   spk    = (const int*)d_in[29];
    float* out = (float*)d_out;
    const int ntarg = out_size >> 7;       // 8192 target nodes

    const size_t NC = (size_t)NNn * CCc;   // 4194304
    float* ws   = (float*)d_ws;
    float* X    = ws;                      // [N,C] f32
    float* S1   = ws + 1 * NC;             // proj partial 0 / vpa out / S1c slices
    float* XV2  = ws + 2 * NC;             // proj partial 1 / xv2
    float* AHc  = ws + 3 * NC;             // compact AH snapshots [3][ntarg][C]
    float* AH0  = ws + 4 * NC;             // per-mask edge-mlp aggregates
    float* AH1  = ws + 5 * NC;
    float* AH2  = ws + 6 * NC;
    float* AH3  = ws + 7 * NC;
    _Float16* P16 = (_Float16*)(ws + 8 * NC);        // NC f16
    _Float16* V16 = P16 + NC;                        // NC f16
    float* ARES = ws + 9 * NC;             // 32768
    int*   cnts = (int*)(ARES + NNn);      // 16 ints
    int*   bsum = cnts + 16;               // 768 + pad
    int*   hist = bsum + 1024;             // 6*32768
    int*   fill = hist + 6 * NNn;          // 6*32768
    int*   base = fill + 6 * NNn;          // 6*32768
    int2*  arena = (int2*)(base + 6 * NNn);
    _Float16* WT = (_Float16*)(arena + ARENA_TOTAL);
    float* AHb[4] = {AH0, AH1, AH2, AH3};

    const int offs[6] = {0, CAP0, CAP0+CAP1, CAP0+CAP1+CAP2,
                         CAP0+CAP1+CAP2+CAP3, CAP0+CAP1+CAP2+CAP3+CAP4};
    const int caps[6] = {CAP0, CAP1, CAP2, CAP3, CAP4, CAP5};

    const _Float16* W011T = WT;
    const _Float16* W012T = WT + 131072;
    const _Float16* WTs   = WT + 262144;
    const _Float16* WlT   = WTs + 12 * 16384;
    const _Float16* WrT   = WTs + 13 * 16384;

    // ---- weight prep + counting-sort CSR build ----
    k_wprep_big<<<1024, 256, 0, stream>>>(W011, W012, WT);
    WSmall wsm;
    for (int i = 0; i < 4; ++i) {
        wsm.p[3*i + 0] = ecW1[i];
        wsm.p[3*i + 1] = ecW1[i] + 16384;
        wsm.p[3*i + 2] = ecW2[i];
    }
    wsm.p[12] = sageWl; wsm.p[13] = sageWr;
    k_wprep_small<<<896, 256, 0, stream>>>(wsm, (_Float16*)WTs);
    k_zero<<<(2 * 6 * NNn) / 1024, 256, 0, stream>>>((float*)hist);  // hist + fill
    k_hist<<<EEe / 256, 256, 0, stream>>>(attr, edst, hist);
    k_scan_a<<<768, 256, 0, stream>>>(hist, base, bsum);
    k_scan_b<<<1, 384, 0, stream>>>(bsum, cnts);
    k_scan_c<<<768, 256, 0, stream>>>(base, bsum);
    k_fill<<<EEe / 256, 256, 0, stream>>>(esrc, edst, attr, base, fill, arena);
    // zero all four AH buffers' atomicMax-path rows (off the branch critical path)
    k_zero4<<<2048, 256, 0, stream>>>(hist, base, AH0, AH1, AH2, AH3);

    // ---- input projection: split-K partials (S1/XV2 free here) + reduce ----
    k_proj<<<512, 512, 0, stream>>>(xv, xa, W011T, W012T, S1, XV2);
    k_reduce<<<(int)(NC / 1024), 256, 0, stream>>>(S1, XV2, b011, b012, X);
    // ---- xa_g (mask 0); S1 fully overwritten ----
    k_csr_vpa<<<2048, 256, 0, stream>>>(X, arena + offs[0], base + 0 * NNn,
                                        hist + 0 * NNn, caps[0], S1);
    // ---- EdgeConv A (mask 1): P/V f16 ----
    k_pv<<<512, 256, 0, stream>>>(S1, WTs, ecb1[0], WTs + 16384, P16, V16);
    k_edge_mlp<<<2048, 256, 0, stream>>>(P16, V16, WTs + 2 * 16384, ecb2[0],
                                         arena + offs[1], cnts + 1, caps[1], AH0);
    k_fc<<<NNn / 4, 256, 0, stream>>>(AH0, fcW, fcb, ARES);
    // ---- xv2 (mask 2); XV2 fully overwritten ----
    k_csr_acv<<<2048, 256, 0, stream>>>(X, ARES, arena + offs[2], base + 2 * NNn,
                                        hist + 2 * NNn, caps[2], XV2);
    // ---- three branches ----
    for (int b = 0; b < 3; ++b) {
        int j = 3 + b;
        const _Float16* Wd = WTs + (3 * (b + 1)) * 16384;
        k_pv<<<512, 256, 0, stream>>>(XV2, Wd, ecb1[b + 1], Wd + 16384, P16, V16);
        k_edge_mlp<<<2048, 256, 0, stream>>>(P16, V16, Wd + 2 * 16384, ecb2[b + 1],
                                             arena + offs[j], cnts + j, caps[j], AHb[b + 1]);
        k_csr_meanc<<<2048, 256, 0, stream>>>(AHb[b + 1], arena + offs[j], base + j * NNn,
                                              hist + j * NNn, caps[j], spk, ntarg,
                                              S1 + (size_t)b * ntarg * 128,
                                              AHc + (size_t)b * ntarg * 128);
    }
    // ---- fused SAGE epilogue -> d_out ----
    k_sage_out<<<ntarg / 64, 256, 0, stream>>>(S1, AHc, WlT, WrT, sagebl, out, ntarg);
}

// Round 12
// 523.418 us; speedup vs baseline: 1.0861x; 1.0592x over previous
//
#include <hip/hip_runtime.h>
#include <cstdint>
#include <cstddef>

#define NVv 192
#define NAa 64
#define TT 128
#define FDd 1024
#define CCc 128
#define EEe 262144
#define NNn 32768

typedef _Float16 f16x8 __attribute__((ext_vector_type(8)));
typedef float f32x4 __attribute__((ext_vector_type(4)));

#define CAP0 65536
#define CAP1 65536
#define CAP2 65536
#define CAP3 98304
#define CAP4 98304
#define CAP5 147456
#define ARENA_TOTAL (CAP0+CAP1+CAP2+CAP3+CAP4+CAP5)   // 540672
#define OFF0 0
#define OFF1 CAP0
#define OFF2 (CAP0+CAP1)
#define OFF3 (CAP0+CAP1+CAP2)
#define OFF4 (CAP0+CAP1+CAP2+CAP3)
#define OFF5 (CAP0+CAP1+CAP2+CAP3+CAP4)

__device__ __forceinline__ void eval_masks(int a, bool m[6]) {
    m[0] = (a == -3); m[1] = (a == -2); m[2] = (a == 3);
    m[3] = (a >= 0) & (a <= 1);
    m[4] = (a >= -1) & (a <= 0);
    m[5] = (a >= -1) & (a <= 1);
}

struct WSmall { const float* p[14]; };
struct PV3  { const _Float16* Wd[3]; const _Float16* Wv[3]; const float* b1[3];
              _Float16* P[3]; _Float16* V[3]; };
struct MLP3 { const _Float16* W2[3]; const float* b2[3];
              const _Float16* P[3]; const _Float16* V[3]; float* AH[3]; };

// ---------------- merged setup: wprep_big | wprep_small | zero(hist+fill) ----------------
__global__ __launch_bounds__(256) void k_setup(
    const float* __restrict__ W011, const float* __restrict__ W012,
    WSmall wsm, _Float16* __restrict__ WT, _Float16* __restrict__ WTs,
    float* __restrict__ hf)
{
    int blk = blockIdx.x, tid = threadIdx.x;
    if (blk < 1024) {                       // wprep_big: 262144 elems
        int idx = blk * 256 + tid;
        int which = idx >> 17;
        int r = idx & 131071;
        int n = r >> 10, k = r & 1023;
        const float* src = which ? W012 : W011;
        WT[idx] = (_Float16)src[k * 128 + n];
    } else if (blk < 1920) {                // wprep_small: 229376 elems
        int idx = (blk - 1024) * 256 + tid;
        int seg = idx >> 14;
        int r = idx & 16383;
        int n = r >> 7, k = r & 127;
        const float* src = wsm.p[seg];
        float v = src[k * 128 + n];
        if (seg < 12 && (seg % 3) == 0) v -= src[16384 + k * 128 + n];
        WTs[idx] = (_Float16)v;
    } else {                                // zero hist+fill: 393216 floats
        size_t i = (size_t)(blk - 1920) * 1024 + (size_t)tid * 4;
        *(float4*)(hf + i) = make_float4(0.f, 0.f, 0.f, 0.f);
    }
}

// ---------------- counting sort phase 1 ----------------
__global__ __launch_bounds__(256) void k_hist(
    const int* __restrict__ attr, const int* __restrict__ edst,
    int* __restrict__ hist)
{
    int e = blockIdx.x * 256 + threadIdx.x;
    int a = attr[e], d = edst[e];
    bool m[6]; eval_masks(a, m);
#pragma unroll
    for (int j = 0; j < 6; ++j)
        if (m[j]) atomicAdd(&hist[j * NNn + d], 1);
}

// ---------------- hierarchical exclusive scan ----------------
__global__ __launch_bounds__(256) void k_scan_a(
    const int* __restrict__ hist, int* __restrict__ base, int* __restrict__ bsum)
{
    __shared__ int wsum[4];
    int idx = blockIdx.x * 256 + threadIdx.x;
    int tid = threadIdx.x, lane = tid & 63, wv = tid >> 6;
    int v = hist[idx];
    int x = v;
#pragma unroll
    for (int off = 1; off < 64; off <<= 1) {
        int y = __shfl_up(x, off, 64);
        if (lane >= off) x += y;
    }
    if (lane == 63) wsum[wv] = x;
    __syncthreads();
    int add = 0;
    for (int w = 0; w < wv; ++w) add += wsum[w];
    base[idx] = add + x - v;
    if (tid == 255) bsum[blockIdx.x] = add + x;
}

__global__ __launch_bounds__(384) void k_scan_b(int* __restrict__ bsum, int* __restrict__ cnts)
{
    int wv = threadIdx.x >> 6;
    int lane = threadIdx.x & 63;
    int run = 0;
#pragma unroll
    for (int c0 = 0; c0 < 128; c0 += 64) {
        int v = bsum[wv * 128 + c0 + lane];
        int x = v;
#pragma unroll
        for (int off = 1; off < 64; off <<= 1) {
            int y = __shfl_up(x, off, 64);
            if (lane >= off) x += y;
        }
        bsum[wv * 128 + c0 + lane] = run + (x - v);
        run += __shfl(x, 63, 64);
    }
    if (lane == 0) cnts[wv] = run;
}

__global__ __launch_bounds__(256) void k_scan_c(int* __restrict__ base, const int* __restrict__ bsum)
{
    base[blockIdx.x * 256 + threadIdx.x] += bsum[blockIdx.x];
}

// ---------------- merged: fill sorted lists | zero AH atomicMax-path rows ----------------
__global__ __launch_bounds__(256) void k_fill_zero(
    const int* __restrict__ esrc, const int* __restrict__ edst,
    const int* __restrict__ attr, const int* __restrict__ base,
    int* __restrict__ fill, int2* __restrict__ arena, const int* __restrict__ hist,
    float* __restrict__ AH0, float* __restrict__ AH1,
    float* __restrict__ AH2, float* __restrict__ AH3)
{
    int blk = blockIdx.x, tid = threadIdx.x;
    if (blk < 1024) {
        int e = blk * 256 + tid;
        int a = attr[e];
        int s = esrc[e], d = edst[e];
        bool m[6]; eval_masks(a, m);
        const int caps[6] = {CAP0, CAP1, CAP2, CAP3, CAP4, CAP5};
        const int offs[6] = {OFF0, OFF1, OFF2, OFF3, OFF4, OFF5};
#pragma unroll
        for (int j = 0; j < 6; ++j) {
            if (m[j]) {
                int pos = base[j * NNn + d] + atomicAdd(&fill[j * NNn + d], 1);
                if (pos < caps[j]) arena[offs[j] + pos] = make_int2(s, d);
            }
        }
    } else {
        int zb = blk - 1024;                  // 0..2047
        int col = tid & 127, sub = tid >> 7;
        const int js[4] = {1, 3, 4, 5};
        float* AHs[4] = {AH0, AH1, AH2, AH3};
        for (int d = zb * 2 + sub; d < NNn; d += 2048 * 2) {
#pragma unroll
            for (int jj = 0; jj < 4; ++jj) {
                int j = js[jj];
                int c = hist[j * NNn + d];
                bool need;
                if (c == 0) need = true;
                else {
                    int b = base[j * NNn + d], e = b + c;
                    need = ((b & 63) == 0) || ((e & 63) == 0) || ((b >> 6) != ((e - 1) >> 6));
                }
                if (need) AHs[jj][(size_t)d * 128 + col] = 0.f;
            }
        }
    }
}

// ---------------- input projection: split-K + double-buffered B ----------------
__global__ __launch_bounds__(512) void k_proj(
    const float* __restrict__ xv, const float* __restrict__ xa,
    const _Float16* __restrict__ BTv, const _Float16* __restrict__ BTa,
    float* __restrict__ Pp0, float* __restrict__ Pp1)
{
    __shared__ _Float16 Bl[2][128][136];
    const int tid = threadIdx.x, wave = tid >> 6, lane = tid & 63;
    const int tile = blockIdx.x >> 1, kh = blockIdx.x & 1;
    const float* A; const _Float16* BT; int mbase, obase;
    if (tile < 192) { A = xv; BT = BTv; mbase = tile * 128; obase = mbase; }
    else { A = xa; BT = BTa; mbase = (tile - 192) * 128; obase = 24576 + mbase; }
    float* Pout = kh ? Pp1 : Pp0;
    const int kbase = kh * 512;

    const int mrow = mbase + wave * 16 + (lane & 15);
    const int fk   = (lane >> 4) * 8;
    f32x4 acc[8];
#pragma unroll
    for (int i = 0; i < 8; ++i) acc[i] = (f32x4){0,0,0,0};

#pragma unroll
    for (int it = 0; it < 4; ++it) {
        int c = it * 512 + tid;
        int n = c >> 4, koff = (c & 15) * 8;
        *(f16x8*)&Bl[0][n][koff] = *(const f16x8*)(BT + (size_t)n * 1024 + kbase + koff);
    }
    f16x8 af[4];
#pragma unroll
    for (int t4 = 0; t4 < 4; ++t4) {
        const float* asrc = A + (size_t)mrow * 1024 + kbase + t4 * 32 + fk;
        float4 a0 = *(const float4*)asrc;
        float4 a1 = *(const float4*)(asrc + 4);
        af[t4] = (f16x8){ (_Float16)a0.x, (_Float16)a0.y, (_Float16)a0.z, (_Float16)a0.w,
                          (_Float16)a1.x, (_Float16)a1.y, (_Float16)a1.z, (_Float16)a1.w };
    }
    __syncthreads();

    for (int kc = 0; kc < 4; ++kc) {
        const int cur = kc & 1;
        f16x8 nf[4];
        if (kc < 3) {
            const int nxt = cur ^ 1;
#pragma unroll
            for (int it = 0; it < 4; ++it) {
                int c = it * 512 + tid;
                int n = c >> 4, koff = (c & 15) * 8;
                *(f16x8*)&Bl[nxt][n][koff] =
                    *(const f16x8*)(BT + (size_t)n * 1024 + kbase + (kc + 1) * 128 + koff);
            }
#pragma unroll
            for (int t4 = 0; t4 < 4; ++t4) {
                const float* asrc = A + (size_t)mrow * 1024 + kbase + (kc + 1) * 128 + t4 * 32 + fk;
                float4 a0 = *(const float4*)asrc;
                float4 a1 = *(const float4*)(asrc + 4);
                nf[t4] = (f16x8){ (_Float16)a0.x, (_Float16)a0.y, (_Float16)a0.z, (_Float16)a0.w,
                                  (_Float16)a1.x, (_Float16)a1.y, (_Float16)a1.z, (_Float16)a1.w };
            }
        }
#pragma unroll
        for (int t4 = 0; t4 < 4; ++t4)
#pragma unroll
            for (int nt = 0; nt < 8; ++nt) {
                f16x8 bf = *(const f16x8*)&Bl[cur][nt * 16 + (lane & 15)][t4 * 32 + fk];
                acc[nt] = __builtin_amdgcn_mfma_f32_16x16x32_f16(af[t4], bf, acc[nt], 0, 0, 0);
            }
        if (kc < 3) {
#pragma unroll
            for (int t4 = 0; t4 < 4; ++t4) af[t4] = nf[t4];
        }
        __syncthreads();
    }
    const int cbase = lane & 15, rloc = (lane >> 4) * 4;
    const int wgrp = wave & 3;
    float* Hsf = (float*)&Bl[0][0][0] + (size_t)wgrp * 16 * 132;
#pragma unroll
    for (int grp = 0; grp < 2; ++grp) {
        if ((wave >> 2) == grp) {
#pragma unroll
            for (int nt = 0; nt < 8; ++nt) {
                int c2 = nt * 16 + cbase;
#pragma unroll
                for (int rr = 0; rr < 4; ++rr)
                    Hsf[(rloc + rr) * 132 + c2] = acc[nt][rr];
            }
#pragma unroll
            for (int it = 0; it < 8; ++it) {
                int id = it * 64 + lane;
                int row = id >> 5, off = (id & 31) * 4;
                float4 v = *(float4*)&Hsf[row * 132 + off];
                *(float4*)&Pout[(size_t)(obase + wave * 16 + row) * 128 + off] = v;
            }
        }
        __syncthreads();
    }
}

// ---------------- reduce: X = Pp0 + Pp1 + bias(row) ----------------
__global__ __launch_bounds__(256) void k_reduce(
    const float* __restrict__ Pp0, const float* __restrict__ Pp1,
    const float* __restrict__ b011, const float* __restrict__ b012,
    float* __restrict__ X)
{
    size_t f = (size_t)blockIdx.x * 256 + threadIdx.x;
    size_t i = f * 4;
    int col = (int)(i & 127);
    int row = (int)(i >> 7);
    const float* bias = (row < 24576) ? b011 : b012;
    float4 a = *(const float4*)(Pp0 + i);
    float4 b = *(const float4*)(Pp1 + i);
    float4 bb = *(const float4*)(bias + col);
    *(float4*)(X + i) = make_float4(a.x + b.x + bb.x, a.y + b.y + bb.y,
                                    a.z + b.z + bb.z, a.w + b.w + bb.w);
}

// ---------------- PV GEMM body (shared by audio + pv3) ----------------
__device__ __forceinline__ void pv_body(
    const float* __restrict__ A, const _Float16* __restrict__ BT1,
    const float* __restrict__ b1, const _Float16* __restrict__ BT2,
    _Float16* __restrict__ P, _Float16* __restrict__ V, int tileblk,
    _Float16 (*Bl1)[136], _Float16 (*Bl2)[136], float* bb)
{
    const int tid = threadIdx.x, wave = tid >> 6, lane = tid & 63;
    const int r0 = tileblk * 64 + wave * 16;
    const int fk = (lane >> 4) * 8;
    const int mrow = r0 + (lane & 15);
    float4 a0[4], a1[4];
#pragma unroll
    for (int t4 = 0; t4 < 4; ++t4) {
        const float* asrc = A + (size_t)mrow * 128 + t4 * 32 + fk;
        a0[t4] = *(const float4*)asrc;
        a1[t4] = *(const float4*)(asrc + 4);
    }
#pragma unroll
    for (int it = 0; it < 8; ++it) {
        int c = it * 256 + tid;
        int n = c >> 4, koff = (c & 15) * 8;
        *(f16x8*)&Bl1[n][koff] = *(const f16x8*)(BT1 + (size_t)n * 128 + koff);
        *(f16x8*)&Bl2[n][koff] = *(const f16x8*)(BT2 + (size_t)n * 128 + koff);
    }
    if (tid < 128) bb[tid] = b1[tid];
    __syncthreads();

    f16x8 af[4];
#pragma unroll
    for (int t4 = 0; t4 < 4; ++t4)
        af[t4] = (f16x8){ (_Float16)a0[t4].x, (_Float16)a0[t4].y, (_Float16)a0[t4].z, (_Float16)a0[t4].w,
                          (_Float16)a1[t4].x, (_Float16)a1[t4].y, (_Float16)a1[t4].z, (_Float16)a1[t4].w };
    f32x4 acc1[8], acc2[8];
#pragma unroll
    for (int i = 0; i < 8; ++i) { acc1[i] = (f32x4){0,0,0,0}; acc2[i] = (f32x4){0,0,0,0}; }
#pragma unroll
    for (int t4 = 0; t4 < 4; ++t4)
#pragma unroll
        for (int nt = 0; nt < 8; ++nt) {
            f16x8 bf1 = *(const f16x8*)&Bl1[nt * 16 + (lane & 15)][t4 * 32 + fk];
            f16x8 bf2 = *(const f16x8*)&Bl2[nt * 16 + (lane & 15)][t4 * 32 + fk];
            acc1[nt] = __builtin_amdgcn_mfma_f32_16x16x32_f16(af[t4], bf1, acc1[nt], 0, 0, 0);
            acc2[nt] = __builtin_amdgcn_mfma_f32_16x16x32_f16(af[t4], bf2, acc2[nt], 0, 0, 0);
        }
    __syncthreads();
    _Float16* Hs = &Bl1[0][0] + (size_t)wave * 16 * 136;
    const int cbase = lane & 15, rloc = (lane >> 4) * 4;
#pragma unroll
    for (int nt = 0; nt < 8; ++nt) {
        int c2 = nt * 16 + cbase;
        float bvv = bb[c2];
#pragma unroll
        for (int rr = 0; rr < 4; ++rr)
            Hs[(rloc + rr) * 136 + c2] = (_Float16)(acc1[nt][rr] + bvv);
    }
#pragma unroll
    for (int it = 0; it < 4; ++it) {
        int id = it * 64 + lane;
        int row = id >> 4, koff = (id & 15) * 8;
        *(f16x8*)&P[(size_t)(r0 + row) * 128 + koff] = *(f16x8*)&Hs[row * 136 + koff];
    }
#pragma unroll
    for (int nt = 0; nt < 8; ++nt) {
        int c2 = nt * 16 + cbase;
#pragma unroll
        for (int rr = 0; rr < 4; ++rr)
            Hs[(rloc + rr) * 136 + c2] = (_Float16)acc2[nt][rr];
    }
#pragma unroll
    for (int it = 0; it < 4; ++it) {
        int id = it * 64 + lane;
        int row = id >> 4, koff = (id & 15) * 8;
        *(f16x8*)&V[(size_t)(r0 + row) * 128 + koff] = *(f16x8*)&Hs[row * 136 + koff];
    }
}

__global__ __launch_bounds__(256) void k_pv(
    const float* __restrict__ A, const _Float16* __restrict__ BT1,
    const float* __restrict__ b1, const _Float16* __restrict__ BT2,
    _Float16* __restrict__ P, _Float16* __restrict__ V)
{
    __shared__ _Float16 Bl1[128][136];
    __shared__ _Float16 Bl2[128][136];
    __shared__ float bb[128];
    pv_body(A, BT1, b1, BT2, P, V, blockIdx.x, Bl1, Bl2, bb);
}

// all 3 branches in one dispatch: 1536 blocks = branch(3) x tile(512)
__global__ __launch_bounds__(256) void k_pv3(const float* __restrict__ A, PV3 p)
{
    __shared__ _Float16 Bl1[128][136];
    __shared__ _Float16 Bl2[128][136];
    __shared__ float bb[128];
    int b = blockIdx.x >> 9, t = blockIdx.x & 511;
    pv_body(A, p.Wd[b], p.b1[b], p.Wv[b], p.P[b], p.V[b], t, Bl1, Bl2, bb);
}

// ---------------- edge MLP body (single tile) ----------------
__device__ __forceinline__ void mlp_tile(
    const _Float16* __restrict__ P, const _Float16* __restrict__ V,
    const _Float16* __restrict__ W2T, const float* __restrict__ b2,
    const int2* __restrict__ list, int cnt, int t, float* __restrict__ agg,
    _Float16 (*Rl)[136], _Float16 (*W2l)[136], float* b2l,
    int2* eSD, unsigned char* gstart, int* gdst, int* ngrS)
{
    const int tid  = threadIdx.x;
    const int wave = tid >> 6;
    const int lane = tid & 63;
#pragma unroll
    for (int i = 0; i < 8; ++i) {
        int c = tid + i * 256;
        int n = c >> 4, koff = (c & 15) * 8;
        *(f16x8*)&W2l[n][koff] = *(const f16x8*)(W2T + n * 128 + koff);
    }
    if (tid < 128) b2l[tid] = b2[tid];
    if (tid < 64) {
        int e = t * 64 + tid;
        eSD[tid] = (e < cnt) ? list[e] : make_int2(0, -1);
    }
    __syncthreads();
    if (tid < 64) {
        int d = eSD[tid].y;
        bool flag = (tid == 0) || (d != eSD[tid - 1].y);
        unsigned long long bm = __ballot(flag);
        int rank = (int)__popcll(bm & ((1ull << tid) - 1ull));
        if (flag) { gstart[rank] = (unsigned char)tid; gdst[rank] = d; }
        if (tid == 0) {
            int ng = (int)__popcll(bm);
            *ngrS = ng;
            gstart[ng] = 64;
        }
    }
    const int rrow = tid >> 4;
    const int rch  = (tid & 15) * 8;
#pragma unroll
    for (int p = 0; p < 4; ++p) {
        int i = p * 16 + rrow;
        int2 sd = eSD[i];
        f16x8 rv = {0, 0, 0, 0, 0, 0, 0, 0};
        if (sd.y >= 0) {
            f16x8 pv = *(const f16x8*)(P + (size_t)sd.y * 128 + rch);
            f16x8 vv = *(const f16x8*)(V + (size_t)sd.x * 128 + rch);
            rv = pv + vv;
#pragma unroll
            for (int q = 0; q < 8; ++q)
                rv[q] = (rv[q] > (_Float16)0.f) ? rv[q] : (_Float16)0.f;
        }
        *(f16x8*)&Rl[i][rch] = rv;
    }
    __syncthreads();

    const int frow  = wave * 16 + (lane & 15);
    const int fq    = (lane >> 4) * 8;
    f32x4 acc[8];
#pragma unroll
    for (int i = 0; i < 8; ++i) acc[i] = (f32x4){0,0,0,0};
#pragma unroll
    for (int t4 = 0; t4 < 4; ++t4) {
        f16x8 af = *(const f16x8*)&Rl[frow][t4 * 32 + fq];
#pragma unroll
        for (int nt = 0; nt < 8; ++nt) {
            f16x8 bf = *(const f16x8*)&W2l[nt * 16 + (lane & 15)][t4 * 32 + fq];
            acc[nt] = __builtin_amdgcn_mfma_f32_16x16x32_f16(af, bf, acc[nt], 0, 0, 0);
        }
    }
    __syncthreads();
    const int rbase = wave * 16 + (lane >> 4) * 4;
    const int cbase = lane & 15;
#pragma unroll
    for (int nt = 0; nt < 8; ++nt) {
        int c2 = nt * 16 + cbase;
        float bv = b2l[c2];
#pragma unroll
        for (int rr = 0; rr < 4; ++rr)
            Rl[rbase + rr][c2] = (_Float16)fmaxf(acc[nt][rr] + bv, 0.f);
    }
    __syncthreads();
    const int col  = tid & 127;
    const int half = tid >> 7;
    int ng = *ngrS;
    for (int g = half; g < ng; g += 2) {
        int s = gstart[g], e = gstart[g + 1];
        int d = gdst[g];
        if (d < 0) continue;
        float m = 0.f;
        for (int i = s; i < e; ++i)
            m = fmaxf(m, (float)Rl[i][col]);
        size_t o = (size_t)d * 128 + col;
        if (s == 0 || e == 64)
            atomicMax((unsigned int*)&agg[o], __float_as_uint(m));
        else
            agg[o] = m;
    }
}

// audio (single mask), grid-stride over tiles
__global__ __launch_bounds__(256, 3) void k_edge_mlp(
    const _Float16* __restrict__ P, const _Float16* __restrict__ V,
    const _Float16* __restrict__ W2T, const float* __restrict__ b2,
    const int2* __restrict__ list, const int* __restrict__ cntp, int cap,
    float* __restrict__ agg)
{
    __shared__ _Float16 Rl[64][136];
    __shared__ _Float16 W2l[128][136];
    __shared__ float b2l[128];
    __shared__ int2 eSD[64];
    __shared__ unsigned char gstart[66];
    __shared__ int gdst[64];
    __shared__ int ngrS;
    int cnt = min(*cntp, cap);
    int ntiles = (cnt + 63) >> 6;
    if ((int)blockIdx.x >= ntiles) return;
    for (int t = blockIdx.x; t < ntiles; t += gridDim.x) {
        if (t != (int)blockIdx.x) __syncthreads();
        mlp_tile(P, V, W2T, b2, list, cnt, t, agg,
                 Rl, W2l, b2l, eSD, gstart, gdst, &ngrS);
    }
}

// all 3 branch masks in one dispatch: 5376 single-tile blocks
__global__ __launch_bounds__(256, 3) void k_edge_mlp3(
    MLP3 p, const int2* __restrict__ arena, const int* __restrict__ cnts)
{
    __shared__ _Float16 Rl[64][136];
    __shared__ _Float16 W2l[128][136];
    __shared__ float b2l[128];
    __shared__ int2 eSD[64];
    __shared__ unsigned char gstart[66];
    __shared__ int gdst[64];
    __shared__ int ngrS;
    const int caps[3] = {CAP3, CAP4, CAP5};
    const int offs[3] = {OFF3, OFF4, OFF5};
    int c0 = min(cnts[3], CAP3), c1 = min(cnts[4], CAP4), c2 = min(cnts[5], CAP5);
    int n0 = (c0 + 63) >> 6, n1 = (c1 + 63) >> 6, n2 = (c2 + 63) >> 6;
    int t = blockIdx.x, b;
    if (t < n0) b = 0;
    else if (t < n0 + n1) { b = 1; t -= n0; }
    else if (t < n0 + n1 + n2) { b = 2; t -= n0 + n1; }
    else return;
    int cnt = min(cnts[3 + b], caps[b]);
    mlp_tile(p.P[b], p.V[b], p.W2[b], p.b2[b], arena + offs[b], cnt, t, p.AH[b],
             Rl, W2l, b2l, eSD, gstart, gdst, &ngrS);
}

// ---------------- CSR gather-reduce kernels ----------------
__global__ __launch_bounds__(256) void k_csr_vpa(
    const float* __restrict__ X, const int2* __restrict__ list,
    const int* __restrict__ base, const int* __restrict__ cntarr, int cap,
    float* __restrict__ S)
{
    int col = threadIdx.x & 127;
    int sub = threadIdx.x >> 7;
    for (int d = blockIdx.x * 2 + sub; d < NNn; d += gridDim.x * 2) {
        int c = cntarr[d];
        float v = 0.f;
        if (c > 0) {
            int b = base[d];
            int end = min(b + c, cap);
            float mx = -3.0e38f;
            for (int i = b; i < end; ++i)
                mx = fmaxf(mx, X[(size_t)list[i].x * 128 + col]);
            v = fmaxf(X[(size_t)d * 128 + col] + mx, 0.f);
        }
        S[(size_t)d * 128 + col] = v;
    }
}

__global__ __launch_bounds__(256) void k_csr_acv(
    const float* __restrict__ X, const float* __restrict__ ares,
    const int2* __restrict__ list,
    const int* __restrict__ base, const int* __restrict__ cntarr, int cap,
    float* __restrict__ S)
{
    int col = threadIdx.x & 127;
    int sub = threadIdx.x >> 7;
    for (int d = blockIdx.x * 2 + sub; d < NNn; d += gridDim.x * 2) {
        int c = cntarr[d];
        float v = 0.f;
        if (c > 0) {
            int b = base[d];
            int end = min(b + c, cap);
            float s = 0.f;
            for (int i = b; i < end; ++i) {
                int sr = list[i].x;
                s += ares[sr] * X[(size_t)sr * 128 + col];
            }
            v = fmaxf(s + (float)c * X[(size_t)d * 128 + col], 0.f);
        }
        S[(size_t)d * 128 + col] = v;
    }
}

// sage mean at target nodes for all 3 branches in one dispatch
__global__ __launch_bounds__(256) void k_meanc3(
    float* const AH1, float* const AH2, float* const AH3,
    const int2* __restrict__ arena,
    const int* __restrict__ base, const int* __restrict__ hist,
    const int* __restrict__ spk, int ntarg,
    float* __restrict__ S1c, float* __restrict__ AHc)
{
    int col = threadIdx.x & 127;
    int sub = threadIdx.x >> 7;
    int step = spk[0] * TT;
    const int caps[3] = {CAP3, CAP4, CAP5};
    const int offs[3] = {OFF3, OFF4, OFF5};
    const float* AHs[3] = {AH1, AH2, AH3};
    int total = 3 * ntarg;
    for (int ci2 = blockIdx.x * 2 + sub; ci2 < total; ci2 += gridDim.x * 2) {
        int b = ci2 / ntarg;
        int ci = ci2 - b * ntarg;
        int j = 3 + b;
        const float* AH = AHs[b];
        const int2* list = arena + offs[b];
        int d = (ci >> 7) * step + (ci & 127);
        int c = hist[j * NNn + d];
        float v = 0.f;
        if (c > 0) {
            int bs = base[j * NNn + d];
            int end = min(bs + c, caps[b]);
            float s = 0.f;
            for (int i = bs; i < end; ++i)
                s += AH[(size_t)list[i].x * 128 + col];
            v = s / (float)c;
        }
        S1c[(size_t)ci2 * 128 + col] = v;
        AHc[(size_t)ci2 * 128 + col] = AH[(size_t)d * 128 + col];
    }
}

// ---------------- fc ----------------
__global__ __launch_bounds__(256) void k_fc(
    const float* __restrict__ A, const float* __restrict__ W,
    const float* __restrict__ b, float* __restrict__ ares)
{
    int node = blockIdx.x * 4 + (threadIdx.x >> 6);
    int lane = threadIdx.x & 63;
    const float* row = A + (size_t)node * 128;
    float v = row[lane] * W[lane] + row[lane + 64] * W[lane + 64];
#pragma unroll
    for (int off = 32; off > 0; off >>= 1) v += __shfl_down(v, off, 64);
    if (lane == 0) ares[node] = v + b[0];
}

// ---------------- fused SAGE output ----------------
__global__ __launch_bounds__(256) void k_sage_out(
    const float* __restrict__ S1c, const float* __restrict__ AHc,
    const _Float16* __restrict__ WlT, const _Float16* __restrict__ WrT,
    const float* __restrict__ bl, float* __restrict__ out, int ntarg)
{
    __shared__ _Float16 Al[64][40];
    __shared__ _Float16 Bl[128][40];
    const int tid  = threadIdx.x;
    const int wave = tid >> 6;
    const int lane = tid & 63;
    const int m0   = blockIdx.x * 64;

    f32x4 accB[8], accO[8];
#pragma unroll
    for (int i = 0; i < 8; ++i) { accB[i] = (f32x4){0,0,0,0}; accO[i] = (f32x4){0,0,0,0}; }

    const int ar = tid >> 2;
    const int ak = (tid & 3) * 8;
    const int fr = wave * 16 + (lane & 15);
    const int fk = (lane >> 4) * 8;
    const int rbase = wave * 16 + (lane >> 4) * 4;
    const int cbase = lane & 15;

    for (int seg = 0; seg < 6; ++seg) {
        int b = seg >> 1, which = seg & 1;
        const float* A = (which ? AHc : S1c) + (size_t)b * ntarg * 128;
        const _Float16* BT = which ? WrT : WlT;
        for (int k0 = 0; k0 < 128; k0 += 32) {
            __syncthreads();
            const float* asrc = A + (size_t)(m0 + ar) * 128 + (k0 + ak);
            float4 a0 = *(const float4*)asrc;
            float4 a1 = *(const float4*)(asrc + 4);
            f16x8 av = { (_Float16)a0.x, (_Float16)a0.y, (_Float16)a0.z, (_Float16)a0.w,
                         (_Float16)a1.x, (_Float16)a1.y, (_Float16)a1.z, (_Float16)a1.w };
            *(f16x8*)&Al[ar][ak] = av;
#pragma unroll
            for (int i = 0; i < 2; ++i) {
                int c = tid + i * 256;
                int n = c >> 2, koff = (c & 3) * 8;
                *(f16x8*)&Bl[n][koff] = *(const f16x8*)(BT + (size_t)n * 128 + k0 + koff);
            }
            __syncthreads();
            f16x8 af = *(const f16x8*)&Al[fr][fk];
#pragma unroll
            for (int nt = 0; nt < 8; ++nt) {
                f16x8 bf = *(const f16x8*)&Bl[nt * 16 + (lane & 15)][fk];
                accB[nt] = __builtin_amdgcn_mfma_f32_16x16x32_f16(af, bf, accB[nt], 0, 0, 0);
            }
        }
        if (which) {
#pragma unroll
            for (int nt = 0; nt < 8; ++nt) {
                int col = nt * 16 + cbase;
                float bv = bl[col];
#pragma unroll
                for (int rr = 0; rr < 4; ++rr) {
                    accO[nt][rr] += fmaxf(accB[nt][rr] + bv, 0.f);
                    accB[nt][rr] = 0.f;
                }
            }
        }
    }
#pragma unroll
    for (int nt = 0; nt < 8; ++nt) {
        int col = nt * 16 + cbase;
#pragma unroll
        for (int rr = 0; rr < 4; ++rr)
            out[(size_t)(m0 + rbase + rr) * 128 + col] = accO[nt][rr];
    }
}

extern "C" void kernel_launch(void* const* d_in, const int* in_sizes, int n_in,
                              void* d_out, int out_size, void* d_ws, size_t ws_size,
                              hipStream_t stream)
{
    (void)in_sizes; (void)n_in; (void)ws_size;
    const float* xv   = (const float*)d_in[0];
    const float* xa   = (const float*)d_in[1];
    const float* W011 = (const float*)d_in[2];
    const float* b011 = (const float*)d_in[3];
    const float* W012 = (const float*)d_in[4];
    const float* b012 = (const float*)d_in[5];
    const float* ecW1[4] = {(const float*)d_in[6],  (const float*)d_in[10],
                            (const float*)d_in[14], (const float*)d_in[18]};
    const float* ecb1[4] = {(const float*)d_in[7],  (const float*)d_in[11],
                            (const float*)d_in[15], (const float*)d_in[19]};
    const float* ecW2[4] = {(const float*)d_in[8],  (const float*)d_in[12],
                            (const float*)d_in[16], (const float*)d_in[20]};
    const float* ecb2[4] = {(const float*)d_in[9],  (const float*)d_in[13],
                            (const float*)d_in[17], (const float*)d_in[21]};
    const float* sageWl = (const float*)d_in[22];
    const float* sagebl = (const float*)d_in[23];
    const float* sageWr = (const float*)d_in[24];
    const float* fcW    = (const float*)d_in[25];
    const float* fcb    = (const float*)d_in[26];
    const int*   esrc   = (const int*)d_in[27];
    const int*   edst   = esrc + EEe;
    const int*   attr   = (const int*)d_in[28];
    const int*   spk    = (const int*)d_in[29];
    float* out = (float*)d_out;
    const int ntarg = out_size >> 7;       // 8192 target nodes

    const size_t NC = (size_t)NNn * CCc;   // 4194304
    float* ws   = (float*)d_ws;
    float* X    = ws;                      // [N,C] f32; later P1/V1 overlay
    float* S1   = ws + 1 * NC;             // proj partial 0 / vpa out / S1c slices
    float* XV2  = ws + 2 * NC;             // proj partial 1 / xv2
    float* AHc  = ws + 3 * NC;             // P2/V2 overlay, then AH compact snapshots
    float* AH0  = ws + 4 * NC;
    float* AH1  = ws + 5 * NC;
    float* AH2  = ws + 6 * NC;
    float* AH3  = ws + 7 * NC;
    _Float16* P0 = (_Float16*)(ws + 8 * NC);
    _Float16* V0 = P0 + NC;
    _Float16* P1 = (_Float16*)X;           // X dead after csr_acv
    _Float16* V1 = P1 + NC;
    _Float16* P2 = (_Float16*)AHc;         // AHc written only by meanc3 (after mlp3)
    _Float16* V2 = P2 + NC;
    float* ARES = ws + 9 * NC;             // 32768
    int*   cnts = (int*)(ARES + NNn);
    int*   bsum = cnts + 16;
    int*   hist = bsum + 1024;             // 6*32768
    int*   fill = hist + 6 * NNn;
    int*   base = fill + 6 * NNn;
    int2*  arena = (int2*)(base + 6 * NNn);
    _Float16* WT = (_Float16*)(arena + ARENA_TOTAL);

    const _Float16* W011T = WT;
    const _Float16* W012T = WT + 131072;
    _Float16* WTs = WT + 262144;
    const _Float16* WlT   = WTs + 12 * 16384;
    const _Float16* WrT   = WTs + 13 * 16384;

    // ---- merged setup + counting-sort CSR build ----
    WSmall wsm;
    for (int i = 0; i < 4; ++i) {
        wsm.p[3*i + 0] = ecW1[i];
        wsm.p[3*i + 1] = ecW1[i] + 16384;
        wsm.p[3*i + 2] = ecW2[i];
    }
    wsm.p[12] = sageWl; wsm.p[13] = sageWr;
    k_setup<<<2304, 256, 0, stream>>>(W011, W012, wsm, WT, WTs, (float*)hist);
    k_hist<<<EEe / 256, 256, 0, stream>>>(attr, edst, hist);
    k_scan_a<<<768, 256, 0, stream>>>(hist, base, bsum);
    k_scan_b<<<1, 384, 0, stream>>>(bsum, cnts);
    k_scan_c<<<768, 256, 0, stream>>>(base, bsum);
    k_fill_zero<<<3072, 256, 0, stream>>>(esrc, edst, attr, base, fill, arena, hist,
                                          AH0, AH1, AH2, AH3);

    // ---- input projection (split-K) + reduce ----
    k_proj<<<512, 512, 0, stream>>>(xv, xa, W011T, W012T, S1, XV2);
    k_reduce<<<(int)(NC / 1024), 256, 0, stream>>>(S1, XV2, b011, b012, X);
    // ---- xa_g (mask 0); S1 fully overwritten ----
    k_csr_vpa<<<2048, 256, 0, stream>>>(X, arena + OFF0, base + 0 * NNn,
                                        hist + 0 * NNn, CAP0, S1);
    // ---- EdgeConv A (mask 1) ----
    k_pv<<<512, 256, 0, stream>>>(S1, WTs, ecb1[0], WTs + 16384, P0, V0);
    k_edge_mlp<<<2048, 256, 0, stream>>>(P0, V0, WTs + 2 * 16384, ecb2[0],
                                         arena + OFF1, cnts + 1, CAP1, AH0);
    k_fc<<<NNn / 4, 256, 0, stream>>>(AH0, fcW, fcb, ARES);
    // ---- xv2 (mask 2); XV2 fully overwritten; last read of X ----
    k_csr_acv<<<2048, 256, 0, stream>>>(X, ARES, arena + OFF2, base + 2 * NNn,
                                        hist + 2 * NNn, CAP2, XV2);
    // ---- three branches merged ----
    PV3 pv3;
    MLP3 m3;
    _Float16* Pb[3] = {P0, P1, P2};
    _Float16* Vb[3] = {V0, V1, V2};
    float* AHb[3] = {AH1, AH2, AH3};
    for (int b = 0; b < 3; ++b) {
        _Float16* Wd = WTs + (3 * (b + 1)) * 16384;
        pv3.Wd[b] = Wd; pv3.Wv[b] = Wd + 16384; pv3.b1[b] = ecb1[b + 1];
        pv3.P[b] = Pb[b]; pv3.V[b] = Vb[b];
        m3.W2[b] = Wd + 2 * 16384; m3.b2[b] = ecb2[b + 1];
        m3.P[b] = Pb[b]; m3.V[b] = Vb[b]; m3.AH[b] = AHb[b];
    }
    k_pv3<<<1536, 256, 0, stream>>>(XV2, pv3);
    k_edge_mlp3<<<5376, 256, 0, stream>>>(m3, arena, cnts);
    k_meanc3<<<2048, 256, 0, stream>>>(AH1, AH2, AH3, arena, base, hist,
                                       spk, ntarg, S1, AHc);
    // ---- fused SAGE epilogue -> d_out ----
    k_sage_out<<<ntarg / 64, 256, 0, stream>>>(S1, AHc, WlT, WrT, sagebl, out, ntarg);
}